// Round 13
// baseline (757.053 us; speedup 1.0000x reference)
//
#include <hip/hip_runtime.h>
#include <hip/hip_bf16.h>

constexpr int NN = 8192;
using uint = unsigned int;

typedef __bf16 bf16x8 __attribute__((ext_vector_type(8)));
typedef float f32x4 __attribute__((ext_vector_type(4)));
typedef float f32x16 __attribute__((ext_vector_type(16)));
typedef unsigned short ushort8_t __attribute__((ext_vector_type(8)));

__device__ __forceinline__ float eluf(float z) { return z > 0.f ? z : __expf(z) - 1.f; }

__device__ __forceinline__ unsigned short bf16_hi(float v) {
  unsigned u = __float_as_uint(v);
  unsigned r = u + 0x7fffu + ((u >> 16) & 1u);
  return (unsigned short)(r >> 16);
}
__device__ __forceinline__ float bf16_tof(unsigned short u) {
  return __uint_as_float(((unsigned)u) << 16);
}

__device__ __forceinline__ uint cvt_pk_bf16(float a, float b) {
  uint r;
  asm("v_cvt_pk_bf16_f32 %0, %1, %2" : "=v"(r) : "v"(a), "v"(b));
  return r;
}

// LDS-only barrier: order LDS ops across the barrier WITHOUT draining vmcnt.
__device__ __forceinline__ void lds_barrier() {
  asm volatile("s_waitcnt lgkmcnt(0)" ::: "memory");
  __builtin_amdgcn_s_barrier();
}

// ---------------------------------------------------------------------------
// GEMM: C[M][NOUT] = A[M][K] @ W[K][NOUT]   (fp32, BM=64,BN=64,BK=16, 4x4 micro)
// ---------------------------------------------------------------------------
template<int K, int NOUT>
__global__ __launch_bounds__(256) void gemm_kernel(
    const float* __restrict__ A, const float* __restrict__ W, float* __restrict__ C) {
  constexpr int BM = 64, BN = 64, BK = 16;
  __shared__ __align__(16) float As[BK][BM + 4];
  __shared__ __align__(16) float Ws[BK][BN];
  const int t = threadIdx.x;
  const int i0 = blockIdx.x * BM;
  const int c0 = blockIdx.y * BN;
  const int tr = t >> 4;
  const int tc = t & 15;
  const int lr = t >> 2;
  const int lk = (t & 3) * 4;
  const int wk = t >> 4;
  const int wc = (t & 15) * 4;
  float acc[4][4] = {};
  for (int k0 = 0; k0 < K; k0 += BK) {
    const float4 a4 = *reinterpret_cast<const float4*>(&A[(size_t)(i0 + lr) * K + k0 + lk]);
    As[lk + 0][lr] = a4.x; As[lk + 1][lr] = a4.y;
    As[lk + 2][lr] = a4.z; As[lk + 3][lr] = a4.w;
    *reinterpret_cast<float4*>(&Ws[wk][wc]) =
        *reinterpret_cast<const float4*>(&W[(size_t)(k0 + wk) * NOUT + c0 + wc]);
    __syncthreads();
    #pragma unroll
    for (int kk = 0; kk < BK; ++kk) {
      const float4 av = *reinterpret_cast<const float4*>(&As[kk][4 * tr]);
      const float4 wv = *reinterpret_cast<const float4*>(&Ws[kk][4 * tc]);
      const float a[4] = {av.x, av.y, av.z, av.w};
      const float w[4] = {wv.x, wv.y, wv.z, wv.w};
      #pragma unroll
      for (int i = 0; i < 4; ++i)
        #pragma unroll
        for (int j = 0; j < 4; ++j) acc[i][j] += a[i] * w[j];
    }
    __syncthreads();
  }
  #pragma unroll
  for (int i = 0; i < 4; ++i) {
    const float4 o = make_float4(acc[i][0], acc[i][1], acc[i][2], acc[i][3]);
    *reinterpret_cast<float4*>(&C[(size_t)(i0 + 4 * tr + i) * NOUT + c0 + 4 * tc]) = o;
  }
}

// ---------------------------------------------------------------------------
// s[i] = h[i].a_self ; n[i] = h[i].a_neigh   (one wave per row)
// ---------------------------------------------------------------------------
template<int FOUT>
__global__ __launch_bounds__(256) void sn_kernel(
    const float* __restrict__ H, const float* __restrict__ a_self,
    const float* __restrict__ a_neigh, float* __restrict__ s, float* __restrict__ n) {
  const int wave = threadIdx.x >> 6;
  const int lane = threadIdx.x & 63;
  const int row = blockIdx.x * 4 + wave;
  float ds = 0.f, dn = 0.f;
  #pragma unroll
  for (int c = lane; c < FOUT; c += 64) {
    const float h = H[(size_t)row * FOUT + c];
    ds += h * a_self[c];
    dn += h * a_neigh[c];
  }
  #pragma unroll
  for (int off = 32; off > 0; off >>= 1) {
    ds += __shfl_down(ds, off);
    dn += __shfl_down(dn, off);
  }
  if (lane == 0) { s[row] = ds; n[row] = dn; }
}

// ---------------------------------------------------------------------------
// Split H (fp32 [N][F]) into hi/lo bf16 in MFMA-staging layout:
//   T[tile=j/32][kc8=0..3][col=0..F-1][e=0..7]  (element j = tile*32+kc8*8+e)
// ---------------------------------------------------------------------------
template<int F>
__global__ __launch_bounds__(256) void split_kernel(
    const float* __restrict__ H, unsigned short* __restrict__ Th,
    unsigned short* __restrict__ Tl) {
  const int t = threadIdx.x;
  const int tile = blockIdx.x;
  const int c = t & (F - 1);
  const int kcb = t / F;
  for (int kc = kcb; kc < 4; kc += 256 / F) {
    ushort8_t hi, lo;
    #pragma unroll
    for (int e = 0; e < 8; ++e) {
      float v = H[(size_t)(tile * 32 + kc * 8 + e) * F + c];
      unsigned short h = bf16_hi(v);
      hi[e] = h;
      lo[e] = bf16_hi(v - bf16_tof(h));
    }
    size_t o = ((size_t)(tile * 4 + kc) * F + c) * 8;
    *reinterpret_cast<ushort8_t*>(&Th[o]) = hi;
    *reinterpret_cast<ushort8_t*>(&Tl[o]) = lo;
  }
}

// ---------------------------------------------------------------------------
// adj (int32 0/1) -> bitmask, word W covers cols [W*32, W*32+32) of a row.
// ---------------------------------------------------------------------------
__global__ __launch_bounds__(256) void mask_kernel(
    const int* __restrict__ adj, uint* __restrict__ Bm) {
  const size_t tg = (size_t)blockIdx.x * 256 + threadIdx.x;
  const int4 a = *reinterpret_cast<const int4*>(&adj[tg * 4]);
  uint nib = (a.x > 0 ? 1u : 0u) | (a.y > 0 ? 2u : 0u) |
             (a.z > 0 ? 4u : 0u) | (a.w > 0 ? 8u : 0u);
  const int lane = threadIdx.x & 63;
  uint v = nib << ((lane & 7) * 4);
  v |= __shfl_xor(v, 1);
  v |= __shfl_xor(v, 2);
  v |= __shfl_xor(v, 4);
  if ((lane & 7) == 0) Bm[tg >> 3] = v;
}

// ---------------------------------------------------------------------------
// combine4: out = elu(sum_4(pO) / sum_4(pL))
// ---------------------------------------------------------------------------
template<int F>
__global__ __launch_bounds__(256) void combine4_kernel(
    const float* __restrict__ pO, const float* __restrict__ pL, float* __restrict__ out) {
  const size_t q = (size_t)blockIdx.x * 256 + threadIdx.x;
  const size_t base = q * 4;
  const int row = (int)(base / F);
  const size_t seg = (size_t)8192 * F;
  const float4 a = *reinterpret_cast<const float4*>(pO + base);
  const float4 b = *reinterpret_cast<const float4*>(pO + seg + base);
  const float4 c = *reinterpret_cast<const float4*>(pO + 2 * seg + base);
  const float4 d = *reinterpret_cast<const float4*>(pO + 3 * seg + base);
  const float il = 1.0f / (pL[row] + pL[8192 + row] + pL[16384 + row] + pL[24576 + row]);
  float4 o;
  o.x = eluf((a.x + b.x + c.x + d.x) * il);
  o.y = eluf((a.y + b.y + c.y + d.y) * il);
  o.z = eluf((a.z + b.z + c.z + d.z) * il);
  o.w = eluf((a.w + b.w + c.w + d.w) * il);
  *reinterpret_cast<float4*>(out + base) = o;
}

// ---------------------------------------------------------------------------
// combine2: out = elu((pO[0]+pO[1]) / (pL[0]+pL[1]))
// ---------------------------------------------------------------------------
template<int F>
__global__ __launch_bounds__(256) void combine_kernel(
    const float* __restrict__ pO, const float* __restrict__ pL, float* __restrict__ out) {
  const size_t q = (size_t)blockIdx.x * 256 + threadIdx.x;
  const size_t base = q * 4;
  const int row = (int)(base / F);
  const float4 a = *reinterpret_cast<const float4*>(pO + base);
  const float4 b = *reinterpret_cast<const float4*>(pO + (size_t)8192 * F + base);
  const float il = 1.0f / (pL[row] + pL[8192 + row]);
  float4 o;
  o.x = eluf((a.x + b.x) * il);
  o.y = eluf((a.y + b.y) * il);
  o.z = eluf((a.z + b.z) * il);
  o.w = eluf((a.w + b.w) * il);
  *reinterpret_cast<float4*>(out + base) = o;
}

// ---------------------------------------------------------------------------
// Layer-1 fused attention v3c. Grid (64,4): block = 128 rows x j-quarter(2048).
// KEY FIX vs R11/R12: __launch_bounds__'s 2nd arg only sets a waves/EU FLOOR;
// the backend still targets max occupancy (8 waves/EU) and capped the
// allocator at 64 VGPRs -> ~50 regs spilled to scratch every STEP (the
// 843 MB WRITE_SIZE). amdgpu_waves_per_eu(4,4) pins min=max=4 waves/EU
// (1 block/CU) -> 128-VGPR budget -> no spills.
// 16 waves: cf = w&7 (32-col frag), rgh = w>>3 (rowgroup pair).
// Full K=64 per wave: 4 slots x bf16x3 x 2 rowgroups = 24 MFMAs, 2 chains;
// B-frags loaded once per STEP and shared by all 4 rowgroups. M/mask
// prefetch 2 tiles deep via e/o register sets. Direct partial-O writes.
// ---------------------------------------------------------------------------
__global__ __launch_bounds__(1024)
__attribute__((amdgpu_waves_per_eu(4, 4)))
void attn1_kernel(
    const float* __restrict__ Mm, const uint* __restrict__ Bm,
    const float* __restrict__ sv, const float* __restrict__ nv,
    const unsigned short* __restrict__ Th, const unsigned short* __restrict__ Tl,
    float* __restrict__ pO, float* __restrict__ pL) {
  constexpr int F = 256, NT = 32;
  __shared__ __align__(16) uint Pa[2][2][4][1056];  // [buf][part][rg][g*132+r*4+q]
  __shared__ __align__(16) float nvs[2048];

  const int t = threadIdx.x;
  const int lane = t & 63;
  const int w = t >> 6;
  const int cf = w & 7;
  const int rgh = w >> 3;
  const int r = t >> 5;              // score row within rowgroup 0..31
  const int p2 = t & 31;             // col pair 2p2,2p2+1 (of 64)
  const int i0 = blockIdx.x * 128;
  const int jh = blockIdx.y;
  const size_t jbase = (size_t)jh * 2048;
  const int jt32 = jh * 64;

  reinterpret_cast<float2*>(nvs)[t] = reinterpret_cast<const float2*>(nv + jbase)[t];

  const float svA = sv[i0 + r];
  const float svB = sv[i0 + 32 + r];
  const float svC = sv[i0 + 64 + r];
  const float svD = sv[i0 + 96 + r];
  const size_t mrowA = (size_t)(i0 + r) * NN + jbase;
  const size_t mrowB = mrowA + (size_t)32 * NN;
  const size_t mrowC = mrowA + (size_t)64 * NN;
  const size_t mrowD = mrowA + (size_t)96 * NN;
  const uint* mkA = Bm + (size_t)(i0 + r) * 256 + jh * 64;
  const uint* mkB = mkA + 32 * 256;
  const uint* mkC = mkA + 64 * 256;
  const uint* mkD = mkA + 96 * 256;
  const int col = cf * 32 + (lane & 31);
  const size_t boA = ((size_t)(lane >> 5) * F + col) * 8;
  const int pidx = (p2 >> 2) * 132 + r * 4 + (p2 & 3);
  const int aoff = (lane & 31) * 4;
  const int mb = 2 * (p2 & 15);
  const int rg0 = rgh * 2, rg1 = rgh * 2 + 1;

  // 2-deep e/o M/mask register sets (tiles 0 and 1)
  float2 MA_e = *reinterpret_cast<const float2*>(&Mm[mrowA + 2 * p2]);
  float2 MB_e = *reinterpret_cast<const float2*>(&Mm[mrowB + 2 * p2]);
  float2 MC_e = *reinterpret_cast<const float2*>(&Mm[mrowC + 2 * p2]);
  float2 MD_e = *reinterpret_cast<const float2*>(&Mm[mrowD + 2 * p2]);
  float2 MA_o = *reinterpret_cast<const float2*>(&Mm[mrowA + 64 + 2 * p2]);
  float2 MB_o = *reinterpret_cast<const float2*>(&Mm[mrowB + 64 + 2 * p2]);
  float2 MC_o = *reinterpret_cast<const float2*>(&Mm[mrowC + 64 + 2 * p2]);
  float2 MD_o = *reinterpret_cast<const float2*>(&Mm[mrowD + 64 + 2 * p2]);
  uint KA_e = mkA[p2 >> 4], KB_e = mkB[p2 >> 4], KC_e = mkC[p2 >> 4], KD_e = mkD[p2 >> 4];
  uint KA_o = mkA[2 + (p2 >> 4)], KB_o = mkB[2 + (p2 >> 4)];
  uint KC_o = mkC[2 + (p2 >> 4)], KD_o = mkD[2 + (p2 >> 4)];

  float rsA = 0.f, rsB = 0.f, rsC = 0.f, rsD = 0.f;
  f32x16 accP, accQ;
  #pragma unroll
  for (int i = 0; i < 16; ++i) { accP[i] = 0.f; accQ[i] = 0.f; }

  __syncthreads();   // nvs staged

#define STEP1(TJ, MAC, KAC, MBC, KBC, MCC, KCC, MDC, KDC)                         \
  {                                                                               \
    const int t_j = (TJ);                                                         \
    const int buf = t_j & 1;                                                      \
    /* 1. B fragments for THIS tile (issued first; consumed after barrier) */     \
    bf16x8 bh[4], bl[4];                                                          \
    _Pragma("unroll")                                                             \
    for (int s = 0; s < 4; ++s) {                                                 \
      const size_t ba = (size_t)(jt32 + 2 * t_j + (s >> 1)) * 8192 + boA +        \
                        (size_t)(s & 1) * 4096;                                   \
      bh[s] = *reinterpret_cast<const bf16x8*>(Th + ba);                          \
      bl[s] = *reinterpret_cast<const bf16x8*>(Tl + ba);                          \
    }                                                                             \
    const float2 NV = *reinterpret_cast<const float2*>(&nvs[t_j * 64 + 2 * p2]);  \
    /* 2. scores for 4 rowgroups (consume M/K) */                                 \
    float e0, e1;                                                                 \
    e0 = (svA + NV.x) * MAC.x; e0 = fmaxf(e0, 0.2f * e0); e0 = fminf(e0, 70.f);   \
    e1 = (svA + NV.y) * MAC.y; e1 = fmaxf(e1, 0.2f * e1); e1 = fminf(e1, 70.f);   \
    const float pA0 = ((KAC >> mb) & 1u) ? __expf(e0) : 0.f;                      \
    const float pA1 = ((KAC >> (mb + 1)) & 1u) ? __expf(e1) : 0.f;                \
    e0 = (svB + NV.x) * MBC.x; e0 = fmaxf(e0, 0.2f * e0); e0 = fminf(e0, 70.f);   \
    e1 = (svB + NV.y) * MBC.y; e1 = fmaxf(e1, 0.2f * e1); e1 = fminf(e1, 70.f);   \
    const float pB0 = ((KBC >> mb) & 1u) ? __expf(e0) : 0.f;                      \
    const float pB1 = ((KBC >> (mb + 1)) & 1u) ? __expf(e1) : 0.f;                \
    e0 = (svC + NV.x) * MCC.x; e0 = fmaxf(e0, 0.2f * e0); e0 = fminf(e0, 70.f);   \
    e1 = (svC + NV.y) * MCC.y; e1 = fmaxf(e1, 0.2f * e1); e1 = fminf(e1, 70.f);   \
    const float pC0 = ((KCC >> mb) & 1u) ? __expf(e0) : 0.f;                      \
    const float pC1 = ((KCC >> (mb + 1)) & 1u) ? __expf(e1) : 0.f;                \
    e0 = (svD + NV.x) * MDC.x; e0 = fmaxf(e0, 0.2f * e0); e0 = fminf(e0, 70.f);   \
    e1 = (svD + NV.y) * MDC.y; e1 = fmaxf(e1, 0.2f * e1); e1 = fminf(e1, 70.f);   \
    const float pD0 = ((KDC >> mb) & 1u) ? __expf(e0) : 0.f;                      \
    const float pD1 = ((KDC >> (mb + 1)) & 1u) ? __expf(e1) : 0.f;                \
    rsA += pA0 + pA1; rsB += pB0 + pB1; rsC += pC0 + pC1; rsD += pD0 + pD1;       \
    /* 3. refill tile+2 DIRECTLY into the dead regs */                            \
    const int jm = (t_j + 2 < NT) ? t_j + 2 : 0;                                  \
    MAC = *reinterpret_cast<const float2*>(&Mm[mrowA + (size_t)jm * 64 + 2 * p2]); \
    MBC = *reinterpret_cast<const float2*>(&Mm[mrowB + (size_t)jm * 64 + 2 * p2]); \
    MCC = *reinterpret_cast<const float2*>(&Mm[mrowC + (size_t)jm * 64 + 2 * p2]); \
    MDC = *reinterpret_cast<const float2*>(&Mm[mrowD + (size_t)jm * 64 + 2 * p2]); \
    KAC = mkA[jm * 2 + (p2 >> 4)];                                                \
    KBC = mkB[jm * 2 + (p2 >> 4)];                                                \
    KCC = mkC[jm * 2 + (p2 >> 4)];                                                \
    KDC = mkD[jm * 2 + (p2 >> 4)];                                                \
    /* 4. pack + P writes */                                                      \
    uint hw, lw;                                                                  \
    hw = cvt_pk_bf16(pA0, pA1);                                                   \
    lw = cvt_pk_bf16(pA0 - __uint_as_float(hw << 16),                             \
                     pA1 - __uint_as_float(hw & 0xffff0000u));                    \
    Pa[buf][0][0][pidx] = hw; Pa[buf][1][0][pidx] = lw;                           \
    hw = cvt_pk_bf16(pB0, pB1);                                                   \
    lw = cvt_pk_bf16(pB0 - __uint_as_float(hw << 16),                             \
                     pB1 - __uint_as_float(hw & 0xffff0000u));                    \
    Pa[buf][0][1][pidx] = hw; Pa[buf][1][1][pidx] = lw;                           \
    hw = cvt_pk_bf16(pC0, pC1);                                                   \
    lw = cvt_pk_bf16(pC0 - __uint_as_float(hw << 16),                             \
                     pC1 - __uint_as_float(hw & 0xffff0000u));                    \
    Pa[buf][0][2][pidx] = hw; Pa[buf][1][2][pidx] = lw;                           \
    hw = cvt_pk_bf16(pD0, pD1);                                                   \
    lw = cvt_pk_bf16(pD0 - __uint_as_float(hw << 16),                             \
                     pD1 - __uint_as_float(hw & 0xffff0000u));                    \
    Pa[buf][0][3][pidx] = hw; Pa[buf][1][3][pidx] = lw;                           \
    lds_barrier();                                                                \
    /* 5. MFMA: 4 slots x (2 rowgroups, 2 chains) x bf16x3 */                     \
    __builtin_amdgcn_s_setprio(1);                                                \
    _Pragma("unroll")                                                             \
    for (int s = 0; s < 4; ++s) {                                                 \
      const int ai = (2 * s + (lane >> 5)) * 132 + aoff;                          \
      const bf16x8 ah0 = *reinterpret_cast<const bf16x8*>(&Pa[buf][0][rg0][ai]);  \
      const bf16x8 al0 = *reinterpret_cast<const bf16x8*>(&Pa[buf][1][rg0][ai]);  \
      const bf16x8 ah1 = *reinterpret_cast<const bf16x8*>(&Pa[buf][0][rg1][ai]);  \
      const bf16x8 al1 = *reinterpret_cast<const bf16x8*>(&Pa[buf][1][rg1][ai]);  \
      accP = __builtin_amdgcn_mfma_f32_32x32x16_bf16(al0, bh[s], accP, 0, 0, 0);  \
      accQ = __builtin_amdgcn_mfma_f32_32x32x16_bf16(al1, bh[s], accQ, 0, 0, 0);  \
      accP = __builtin_amdgcn_mfma_f32_32x32x16_bf16(ah0, bl[s], accP, 0, 0, 0);  \
      accQ = __builtin_amdgcn_mfma_f32_32x32x16_bf16(ah1, bl[s], accQ, 0, 0, 0);  \
      accP = __builtin_amdgcn_mfma_f32_32x32x16_bf16(ah0, bh[s], accP, 0, 0, 0);  \
      accQ = __builtin_amdgcn_mfma_f32_32x32x16_bf16(ah1, bh[s], accQ, 0, 0, 0);  \
    }                                                                             \
    __builtin_amdgcn_s_setprio(0);                                                \
  }

  for (int tj = 0; tj < NT; tj += 2) {
    STEP1(tj,     MA_e, KA_e, MB_e, KB_e, MC_e, KC_e, MD_e, KD_e)
    STEP1(tj + 1, MA_o, KA_o, MB_o, KB_o, MC_o, KC_o, MD_o, KD_o)
  }
#undef STEP1

  // rowsums (32 col-threads per row; xor<32 stays within the 32-lane half)
  #pragma unroll
  for (int off = 1; off < 32; off <<= 1) {
    rsA += __shfl_xor(rsA, off);
    rsB += __shfl_xor(rsB, off);
    rsC += __shfl_xor(rsC, off);
    rsD += __shfl_xor(rsD, off);
  }
  if (p2 == 0) {
    const size_t b = (size_t)jh * 8192 + i0 + r;
    pL[b] = rsA; pL[b + 32] = rsB; pL[b + 64] = rsC; pL[b + 96] = rsD;
  }

  // direct partial-O writes (no k-reduce)
  float* po = pO + (size_t)jh * 8192 * F;
  #pragma unroll
  for (int reg = 0; reg < 16; ++reg) {
    const int rr = (reg & 3) + 8 * (reg >> 2) + 4 * (lane >> 5);
    po[(size_t)(i0 + rgh * 64 + rr) * F + col] = accP[reg];
    po[(size_t)(i0 + rgh * 64 + 32 + rr) * F + col] = accQ[reg];
  }
}

// ---------------------------------------------------------------------------
// Layer-2 fused attention (R9 structure, plain loads).
// Grid (128,2): 64 rows x j-half, 1024 thr.
// ---------------------------------------------------------------------------
__global__ __launch_bounds__(1024, 4) void attn2_kernel(
    const float* __restrict__ Mm, const uint* __restrict__ Bm,
    const float* __restrict__ sv, const float* __restrict__ nv,
    const unsigned short* __restrict__ Th, const unsigned short* __restrict__ Tl,
    float* __restrict__ pO, float* __restrict__ pL) {
  constexpr int F = 64, NT = 4096 / 64;
  __shared__ __align__(16) uint Pa[2][2][2][8 * 132];
  __shared__ __align__(16) float nvs[4096];
  __shared__ float l_lds[64];

  const int t = threadIdx.x;
  const int lane = t & 63;
  const int w = t >> 6;
  const int rb = w & 1;
  const int cf = (w >> 1) & 3;
  const int ks = w >> 3;
  const int r = t >> 5;
  const int p2 = t & 31;
  const int i0 = blockIdx.x * 64;
  const int jh = blockIdx.y;
  const size_t jbase = (size_t)jh * 4096;
  const int jt = jh * 128;

  reinterpret_cast<float4*>(nvs)[t] = reinterpret_cast<const float4*>(nv + jbase)[t];

  const float svrA = sv[i0 + r];
  const float svrB = sv[i0 + 32 + r];
  const size_t mrowA = (size_t)(i0 + r) * NN + jbase;
  const size_t mrowB = mrowA + (size_t)32 * NN;
  const uint* mkrowA = Bm + (size_t)(i0 + r) * (NN / 32) + jh * 128;
  const uint* mkrowB = mkrowA + (size_t)32 * (NN / 32);
  const int col = cf * 16 + (lane & 15);
  const size_t bo2 = ((size_t)(lane >> 4) * F + col) * 8;
  const int pidx = (p2 >> 2) * 132 + r * 4 + (p2 & 3);
  const int aidx = (ks * 4 + (lane >> 4)) * 132 + (rb * 16 + (lane & 15)) * 4;

  float2 MA_e = *reinterpret_cast<const float2*>(&Mm[mrowA + 2 * p2]);
  float2 MA_o = *reinterpret_cast<const float2*>(&Mm[mrowA + 64 + 2 * p2]);
  float2 MB_e = *reinterpret_cast<const float2*>(&Mm[mrowB + 2 * p2]);
  float2 MB_o = *reinterpret_cast<const float2*>(&Mm[mrowB + 64 + 2 * p2]);
  uint mkA_e = mkrowA[p2 >> 4];
  uint mkA_o = mkrowA[2 + (p2 >> 4)];
  uint mkB_e = mkrowB[p2 >> 4];
  uint mkB_o = mkrowB[2 + (p2 >> 4)];
  const size_t tb0 = (size_t)(jt + ks) * 2048;
  bf16x8 bh_e = *reinterpret_cast<const bf16x8*>(Th + tb0 + bo2);
  bf16x8 bl_e = *reinterpret_cast<const bf16x8*>(Tl + tb0 + bo2);
  bf16x8 bh_o, bl_o;

  float rsumA = 0.f, rsumB = 0.f;
  f32x4 accA = {0.f, 0.f, 0.f, 0.f}, accA2 = {0.f, 0.f, 0.f, 0.f};
  f32x4 accB = {0.f, 0.f, 0.f, 0.f}, accB2 = {0.f, 0.f, 0.f, 0.f};

  __syncthreads();   // nvs staged

  float2 nv_e = *reinterpret_cast<const float2*>(&nvs[2 * p2]);
  float2 nv_o = *reinterpret_cast<const float2*>(&nvs[64 + 2 * p2]);

#define STEP2(TJ, MCA, MKA, MCB, MKB, NVC, BHC, BLC, BHN, BLN)                    \
  {                                                                               \
    const int t_j = (TJ);                                                         \
    const int jb = (t_j + 1 < NT) ? t_j + 1 : 0;                                  \
    const size_t tb = (size_t)(jt + 2 * jb + ks) * 2048;                          \
    BHN = *reinterpret_cast<const bf16x8*>(Th + tb + bo2);                        \
    BLN = *reinterpret_cast<const bf16x8*>(Tl + tb + bo2);                        \
    float e0 = (svrA + NVC.x) * MCA.x; e0 = fmaxf(e0, 0.2f * e0); e0 = fminf(e0, 70.f); \
    float e1 = (svrA + NVC.y) * MCA.y; e1 = fmaxf(e1, 0.2f * e1); e1 = fminf(e1, 70.f); \
    float e2 = (svrB + NVC.x) * MCB.x; e2 = fmaxf(e2, 0.2f * e2); e2 = fminf(e2, 70.f); \
    float e3 = (svrB + NVC.y) * MCB.y; e3 = fmaxf(e3, 0.2f * e3); e3 = fminf(e3, 70.f); \
    const float pA0 = ((MKA >> (2 * (p2 & 15))) & 1u) ? __expf(e0) : 0.f;         \
    const float pA1 = ((MKA >> (2 * (p2 & 15) + 1)) & 1u) ? __expf(e1) : 0.f;     \
    const float pB0 = ((MKB >> (2 * (p2 & 15))) & 1u) ? __expf(e2) : 0.f;         \
    const float pB1 = ((MKB >> (2 * (p2 & 15) + 1)) & 1u) ? __expf(e3) : 0.f;     \
    rsumA += pA0 + pA1; rsumB += pB0 + pB1;                                       \
    const int jm = (t_j + 2 < NT) ? t_j + 2 : 0;                                  \
    MCA = *reinterpret_cast<const float2*>(&Mm[mrowA + (size_t)jm * 64 + 2 * p2]); \
    MKA = mkrowA[jm * 2 + (p2 >> 4)];                                             \
    MCB = *reinterpret_cast<const float2*>(&Mm[mrowB + (size_t)jm * 64 + 2 * p2]); \
    MKB = mkrowB[jm * 2 + (p2 >> 4)];                                             \
    NVC = *reinterpret_cast<const float2*>(&nvs[jm * 64 + 2 * p2]);               \
    const uint hwA = cvt_pk_bf16(pA0, pA1);                                       \
    const uint lwA = cvt_pk_bf16(pA0 - __uint_as_float(hwA << 16),                \
                                 pA1 - __uint_as_float(hwA & 0xffff0000u));       \
    const uint hwB = cvt_pk_bf16(pB0, pB1);                                       \
    const uint lwB = cvt_pk_bf16(pB0 - __uint_as_float(hwB << 16),                \
                                 pB1 - __uint_as_float(hwB & 0xffff0000u));       \
    Pa[t_j & 1][0][0][pidx] = hwA;                                                \
    Pa[t_j & 1][1][0][pidx] = lwA;                                                \
    Pa[t_j & 1][0][1][pidx] = hwB;                                                \
    Pa[t_j & 1][1][1][pidx] = lwB;                                                \
    lds_barrier();                                                                \
    const bf16x8 ahA = *reinterpret_cast<const bf16x8*>(&Pa[t_j & 1][0][0][aidx]); \
    const bf16x8 alA = *reinterpret_cast<const bf16x8*>(&Pa[t_j & 1][1][0][aidx]); \
    const bf16x8 ahB = *reinterpret_cast<const bf16x8*>(&Pa[t_j & 1][0][1][aidx]); \
    const bf16x8 alB = *reinterpret_cast<const bf16x8*>(&Pa[t_j & 1][1][1][aidx]); \
    __builtin_amdgcn_s_setprio(1);                                                \
    accA  = __builtin_amdgcn_mfma_f32_16x16x32_bf16(alA, BHC, accA, 0, 0, 0);     \
    accB  = __builtin_amdgcn_mfma_f32_16x16x32_bf16(alB, BHC, accB, 0, 0, 0);     \
    accA2 = __builtin_amdgcn_mfma_f32_16x16x32_bf16(ahA, BLC, accA2, 0, 0, 0);    \
    accB2 = __builtin_amdgcn_mfma_f32_16x16x32_bf16(ahB, BLC, accB2, 0, 0, 0);    \
    accA  = __builtin_amdgcn_mfma_f32_16x16x32_bf16(ahA, BHC, accA, 0, 0, 0);     \
    accB  = __builtin_amdgcn_mfma_f32_16x16x32_bf16(ahB, BHC, accB, 0, 0, 0);     \
    __builtin_amdgcn_s_setprio(0);                                                \
  }

  for (int tj = 0; tj < NT; tj += 2) {
    STEP2(tj,     MA_e, mkA_e, MB_e, mkB_e, nv_e, bh_e, bl_e, bh_o, bl_o)
    STEP2(tj + 1, MA_o, mkA_o, MB_o, mkB_o, nv_o, bh_o, bl_o, bh_e, bl_e)
  }
#undef STEP2

  #pragma unroll
  for (int off = 1; off < 32; off <<= 1) {
    rsumA += __shfl_xor(rsumA, off);
    rsumB += __shfl_xor(rsumB, off);
  }
  if (p2 == 0) { l_lds[r] = rsumA; l_lds[32 + r] = rsumB; }
  __syncthreads();
  if (t < 64) pL[(size_t)jh * 8192 + i0 + t] = l_lds[t];

  float* scratch = nvs;
  if (ks == 1) {
    #pragma unroll
    for (int reg = 0; reg < 4; ++reg)
      scratch[(w & 7) * 256 + reg * 64 + lane] = accA[reg] + accA2[reg];
  }
  __syncthreads();
  if (ks == 0) {
    #pragma unroll
    for (int reg = 0; reg < 4; ++reg) {
      const int row = rb * 16 + (lane >> 4) * 4 + reg;
      pO[(size_t)jh * 8192 * F + (size_t)(i0 + row) * F + col] =
          accA[reg] + accA2[reg] + scratch[(w & 7) * 256 + reg * 64 + lane];
    }
  }
  __syncthreads();
  if (ks == 1) {
    #pragma unroll
    for (int reg = 0; reg < 4; ++reg)
      scratch[(w & 7) * 256 + reg * 64 + lane] = accB[reg] + accB2[reg];
  }
  __syncthreads();
  if (ks == 0) {
    #pragma unroll
    for (int reg = 0; reg < 4; ++reg) {
      const int row = rb * 16 + (lane >> 4) * 4 + reg;
      pO[(size_t)jh * 8192 * F + (size_t)(i0 + 32 + row) * F + col] =
          accB[reg] + accB2[reg] + scratch[(w & 7) * 256 + reg * 64 + lane];
    }
  }
}

// ---------------------------------------------------------------------------
extern "C" void kernel_launch(void* const* d_in, const int* in_sizes, int n_in,
                              void* d_out, int out_size, void* d_ws, size_t ws_size,
                              hipStream_t stream) {
  const float* x   = (const float*)d_in[0];
  const int*   adj = (const int*)  d_in[1];
  const float* Mm  = (const float*)d_in[2];
  const float* W0  = (const float*)d_in[3];
  const float* as0 = (const float*)d_in[4];
  const float* an0 = (const float*)d_in[5];
  const float* W1  = (const float*)d_in[6];
  const float* as1 = (const float*)d_in[7];
  const float* an1 = (const float*)d_in[8];
  float* out = (float*)d_out;

  char* ws = (char*)d_ws;
  const size_t MB = 1048576;
  const size_t KB = 1024;
  float* h0  = (float*)(ws);                              // 8 MB (dead after split1)
  uint*  Bm  = (uint*) (ws);                              // 8 MB (after h0 dead)
  float* x1  = (float*)(ws + 8 * MB);                     // 8 MB
  float* h1  = (float*)(ws + 16 * MB);                    // 2 MB
  unsigned short* Th0 = (unsigned short*)(ws + 18 * MB);  // 4 MB
  unsigned short* Tl0 = (unsigned short*)(ws + 22 * MB);  // 4 MB
  unsigned short* Th1 = (unsigned short*)(ws + 26 * MB);  // 1 MB
  unsigned short* Tl1 = (unsigned short*)(ws + 27 * MB);  // 1 MB
  float* s0  = (float*)(ws + 28 * MB);
  float* n0  = (float*)(ws + 28 * MB + 32 * KB);
  float* s1  = (float*)(ws + 28 * MB + 64 * KB);
  float* n1  = (float*)(ws + 28 * MB + 96 * KB);
  float* pL1 = (float*)(ws + 28 * MB + 128 * KB);         // 128 KB [4][8192]
  float* pL2 = (float*)(ws + 28 * MB + 256 * KB);         // 64 KB  [2][8192]
  float* pO1 = (float*)(ws + 29 * MB);                    // 32 MB [4][8192][256]
  float* pO2 = (float*)(ws + 29 * MB);                    // 4 MB  [2][8192][64] (pO1 dead)

  // ---- layer 1 ----
  gemm_kernel<512, 256><<<dim3(128, 4), dim3(256), 0, stream>>>(x, W0, h0);
  sn_kernel<256><<<dim3(2048), dim3(256), 0, stream>>>(h0, as0, an0, s0, n0);
  split_kernel<256><<<dim3(256), dim3(256), 0, stream>>>(h0, Th0, Tl0);
  mask_kernel<<<dim3(65536), dim3(256), 0, stream>>>(adj, Bm);   // h0 now dead
  attn1_kernel<<<dim3(64, 4), dim3(1024), 0, stream>>>(Mm, Bm, s0, n0, Th0, Tl0, pO1, pL1);
  combine4_kernel<256><<<dim3(2048), dim3(256), 0, stream>>>(pO1, pL1, x1);
  // ---- layer 2 ----
  gemm_kernel<256, 64><<<dim3(128, 1), dim3(256), 0, stream>>>(x1, W1, h1);
  sn_kernel<64><<<dim3(2048), dim3(256), 0, stream>>>(h1, as1, an1, s1, n1);
  split_kernel<64><<<dim3(256), dim3(256), 0, stream>>>(h1, Th1, Tl1);
  attn2_kernel<<<dim3(128, 2), dim3(1024), 0, stream>>>(Mm, Bm, s1, n1, Th1, Tl1, pO2, pL2);
  combine_kernel<64><<<dim3(512), dim3(256), 0, stream>>>(pO2, pL2, out);
}

// Round 14
// 336.916 us; speedup vs baseline: 2.2470x; 2.2470x over previous
//
#include <hip/hip_runtime.h>
#include <hip/hip_bf16.h>

constexpr int NN = 8192;
using uint = unsigned int;

typedef __bf16 bf16x8 __attribute__((ext_vector_type(8)));
typedef float f32x4 __attribute__((ext_vector_type(4)));
typedef float f32x16 __attribute__((ext_vector_type(16)));
typedef unsigned short ushort8_t __attribute__((ext_vector_type(8)));

__device__ __forceinline__ float eluf(float z) { return z > 0.f ? z : __expf(z) - 1.f; }

__device__ __forceinline__ unsigned short bf16_hi(float v) {
  unsigned u = __float_as_uint(v);
  unsigned r = u + 0x7fffu + ((u >> 16) & 1u);
  return (unsigned short)(r >> 16);
}
__device__ __forceinline__ float bf16_tof(unsigned short u) {
  return __uint_as_float(((unsigned)u) << 16);
}

__device__ __forceinline__ uint cvt_pk_bf16(float a, float b) {
  uint r;
  asm("v_cvt_pk_bf16_f32 %0, %1, %2" : "=v"(r) : "v"(a), "v"(b));
  return r;
}

// LDS-only barrier: order LDS ops across the barrier WITHOUT draining vmcnt.
__device__ __forceinline__ void lds_barrier() {
  asm volatile("s_waitcnt lgkmcnt(0)" ::: "memory");
  __builtin_amdgcn_s_barrier();
}

// ---------------------------------------------------------------------------
// GEMM: C[M][NOUT] = A[M][K] @ W[K][NOUT]   (fp32, BM=64,BN=64,BK=16, 4x4 micro)
// ---------------------------------------------------------------------------
template<int K, int NOUT>
__global__ __launch_bounds__(256) void gemm_kernel(
    const float* __restrict__ A, const float* __restrict__ W, float* __restrict__ C) {
  constexpr int BM = 64, BN = 64, BK = 16;
  __shared__ __align__(16) float As[BK][BM + 4];
  __shared__ __align__(16) float Ws[BK][BN];
  const int t = threadIdx.x;
  const int i0 = blockIdx.x * BM;
  const int c0 = blockIdx.y * BN;
  const int tr = t >> 4;
  const int tc = t & 15;
  const int lr = t >> 2;
  const int lk = (t & 3) * 4;
  const int wk = t >> 4;
  const int wc = (t & 15) * 4;
  float acc[4][4] = {};
  for (int k0 = 0; k0 < K; k0 += BK) {
    const float4 a4 = *reinterpret_cast<const float4*>(&A[(size_t)(i0 + lr) * K + k0 + lk]);
    As[lk + 0][lr] = a4.x; As[lk + 1][lr] = a4.y;
    As[lk + 2][lr] = a4.z; As[lk + 3][lr] = a4.w;
    *reinterpret_cast<float4*>(&Ws[wk][wc]) =
        *reinterpret_cast<const float4*>(&W[(size_t)(k0 + wk) * NOUT + c0 + wc]);
    __syncthreads();
    #pragma unroll
    for (int kk = 0; kk < BK; ++kk) {
      const float4 av = *reinterpret_cast<const float4*>(&As[kk][4 * tr]);
      const float4 wv = *reinterpret_cast<const float4*>(&Ws[kk][4 * tc]);
      const float a[4] = {av.x, av.y, av.z, av.w};
      const float w[4] = {wv.x, wv.y, wv.z, wv.w};
      #pragma unroll
      for (int i = 0; i < 4; ++i)
        #pragma unroll
        for (int j = 0; j < 4; ++j) acc[i][j] += a[i] * w[j];
    }
    __syncthreads();
  }
  #pragma unroll
  for (int i = 0; i < 4; ++i) {
    const float4 o = make_float4(acc[i][0], acc[i][1], acc[i][2], acc[i][3]);
    *reinterpret_cast<float4*>(&C[(size_t)(i0 + 4 * tr + i) * NOUT + c0 + 4 * tc]) = o;
  }
}

// ---------------------------------------------------------------------------
// s[i] = h[i].a_self ; n[i] = h[i].a_neigh   (one wave per row)
// ---------------------------------------------------------------------------
template<int FOUT>
__global__ __launch_bounds__(256) void sn_kernel(
    const float* __restrict__ H, const float* __restrict__ a_self,
    const float* __restrict__ a_neigh, float* __restrict__ s, float* __restrict__ n) {
  const int wave = threadIdx.x >> 6;
  const int lane = threadIdx.x & 63;
  const int row = blockIdx.x * 4 + wave;
  float ds = 0.f, dn = 0.f;
  #pragma unroll
  for (int c = lane; c < FOUT; c += 64) {
    const float h = H[(size_t)row * FOUT + c];
    ds += h * a_self[c];
    dn += h * a_neigh[c];
  }
  #pragma unroll
  for (int off = 32; off > 0; off >>= 1) {
    ds += __shfl_down(ds, off);
    dn += __shfl_down(dn, off);
  }
  if (lane == 0) { s[row] = ds; n[row] = dn; }
}

// ---------------------------------------------------------------------------
// Split H (fp32 [N][F]) into hi/lo bf16 in MFMA-staging layout:
//   T[tile=j/32][kc8=0..3][col=0..F-1][e=0..7]  (element j = tile*32+kc8*8+e)
// ---------------------------------------------------------------------------
template<int F>
__global__ __launch_bounds__(256) void split_kernel(
    const float* __restrict__ H, unsigned short* __restrict__ Th,
    unsigned short* __restrict__ Tl) {
  const int t = threadIdx.x;
  const int tile = blockIdx.x;
  const int c = t & (F - 1);
  const int kcb = t / F;
  for (int kc = kcb; kc < 4; kc += 256 / F) {
    ushort8_t hi, lo;
    #pragma unroll
    for (int e = 0; e < 8; ++e) {
      float v = H[(size_t)(tile * 32 + kc * 8 + e) * F + c];
      unsigned short h = bf16_hi(v);
      hi[e] = h;
      lo[e] = bf16_hi(v - bf16_tof(h));
    }
    size_t o = ((size_t)(tile * 4 + kc) * F + c) * 8;
    *reinterpret_cast<ushort8_t*>(&Th[o]) = hi;
    *reinterpret_cast<ushort8_t*>(&Tl[o]) = lo;
  }
}

// ---------------------------------------------------------------------------
// adj (int32 0/1) -> bitmask, word W covers cols [W*32, W*32+32) of a row.
// ---------------------------------------------------------------------------
__global__ __launch_bounds__(256) void mask_kernel(
    const int* __restrict__ adj, uint* __restrict__ Bm) {
  const size_t tg = (size_t)blockIdx.x * 256 + threadIdx.x;
  const int4 a = *reinterpret_cast<const int4*>(&adj[tg * 4]);
  uint nib = (a.x > 0 ? 1u : 0u) | (a.y > 0 ? 2u : 0u) |
             (a.z > 0 ? 4u : 0u) | (a.w > 0 ? 8u : 0u);
  const int lane = threadIdx.x & 63;
  uint v = nib << ((lane & 7) * 4);
  v |= __shfl_xor(v, 1);
  v |= __shfl_xor(v, 2);
  v |= __shfl_xor(v, 4);
  if ((lane & 7) == 0) Bm[tg >> 3] = v;
}

// ---------------------------------------------------------------------------
// combine: out = elu((pO[0]+pO[1]) / (pL[0]+pL[1]))   (j-half partial merge)
// ---------------------------------------------------------------------------
template<int F>
__global__ __launch_bounds__(256) void combine_kernel(
    const float* __restrict__ pO, const float* __restrict__ pL, float* __restrict__ out) {
  const size_t q = (size_t)blockIdx.x * 256 + threadIdx.x;
  const size_t base = q * 4;
  const int row = (int)(base / F);
  const float4 a = *reinterpret_cast<const float4*>(pO + base);
  const float4 b = *reinterpret_cast<const float4*>(pO + (size_t)8192 * F + base);
  const float il = 1.0f / (pL[row] + pL[8192 + row]);
  float4 o;
  o.x = eluf((a.x + b.x) * il);
  o.y = eluf((a.y + b.y) * il);
  o.z = eluf((a.z + b.z) * il);
  o.w = eluf((a.w + b.w) * il);
  *reinterpret_cast<float4*>(out + base) = o;
}

// ---------------------------------------------------------------------------
// Layer-1 fused attention. Grid (128,2): block = 64 rows (2 rowgroups) x j-half.
// 1024 thr (16 waves): cf = w&7 (32-col frag), ks = w>>3 (k-half of 64-tile).
// Per STEP: scores for both rowgroups (4/thread), B-frags loaded ONCE and
// reused by both rowgroups' MFMAs (12 MFMAs, 2 chains). Partial out + rowsum.
// ---------------------------------------------------------------------------
__global__ __launch_bounds__(1024, 4) void attn1_kernel(
    const float* __restrict__ Mm, const uint* __restrict__ Bm,
    const float* __restrict__ sv, const float* __restrict__ nv,
    const unsigned short* __restrict__ Th, const unsigned short* __restrict__ Tl,
    float* __restrict__ pO, float* __restrict__ pL) {
  constexpr int F = 256, NT = 4096 / 64;
  __shared__ __align__(16) uint Pa[2][2][2][8 * 132];  // [buf][part][rg][g*132+r*4+q]
  __shared__ __align__(16) float nvs[8192];            // [0..4095]=nv half; full=scratch
  __shared__ float l_lds[64];

  const int t = threadIdx.x;
  const int lane = t & 63;
  const int w = t >> 6;
  const int cf = w & 7;
  const int ks = w >> 3;
  const int r = t >> 5;              // score row 0..31 (per rowgroup)
  const int p2 = t & 31;             // col pair 2p2,2p2+1 (of 64)
  const int i0 = blockIdx.x * 64;
  const int jh = blockIdx.y;
  const size_t jbase = (size_t)jh * 4096;
  const int jt = jh * 128;           // tile32 base

  reinterpret_cast<float4*>(nvs)[t] = reinterpret_cast<const float4*>(nv + jbase)[t];

  const float svrA = sv[i0 + r];
  const float svrB = sv[i0 + 32 + r];
  const size_t mrowA = (size_t)(i0 + r) * NN + jbase;
  const size_t mrowB = mrowA + (size_t)32 * NN;
  const uint* mkrowA = Bm + (size_t)(i0 + r) * (NN / 32) + jh * 128;
  const uint* mkrowB = mkrowA + (size_t)32 * (NN / 32);
  const int col = cf * 32 + (lane & 31);
  const size_t bo0 = ((size_t)(lane >> 5) * F + col) * 8;
  const int pidx = (p2 >> 2) * 132 + r * 4 + (p2 & 3);
  const int aidx = (ks * 4 + (lane >> 5)) * 132 + (lane & 31) * 4;

  float2 MA_e = *reinterpret_cast<const float2*>(&Mm[mrowA + 2 * p2]);
  float2 MA_o = *reinterpret_cast<const float2*>(&Mm[mrowA + 64 + 2 * p2]);
  float2 MB_e = *reinterpret_cast<const float2*>(&Mm[mrowB + 2 * p2]);
  float2 MB_o = *reinterpret_cast<const float2*>(&Mm[mrowB + 64 + 2 * p2]);
  uint mkA_e = mkrowA[p2 >> 4];
  uint mkA_o = mkrowA[2 + (p2 >> 4)];
  uint mkB_e = mkrowB[p2 >> 4];
  uint mkB_o = mkrowB[2 + (p2 >> 4)];
  const size_t tb0 = (size_t)(jt + ks) * 8192;
  bf16x8 bh0_e = *reinterpret_cast<const bf16x8*>(Th + tb0 + bo0);
  bf16x8 bl0_e = *reinterpret_cast<const bf16x8*>(Tl + tb0 + bo0);
  bf16x8 bh1_e = *reinterpret_cast<const bf16x8*>(Th + tb0 + bo0 + 4096);
  bf16x8 bl1_e = *reinterpret_cast<const bf16x8*>(Tl + tb0 + bo0 + 4096);
  bf16x8 bh0_o, bl0_o, bh1_o, bl1_o;

  float rsumA = 0.f, rsumB = 0.f;
  f32x16 accA, accB;
  #pragma unroll
  for (int i = 0; i < 16; ++i) { accA[i] = 0.f; accB[i] = 0.f; }

  __syncthreads();   // nvs staged

  float2 nv_e = *reinterpret_cast<const float2*>(&nvs[2 * p2]);
  float2 nv_o = *reinterpret_cast<const float2*>(&nvs[64 + 2 * p2]);

#define STEP1(TJ, MCA, MKA, MCB, MKB, NVC, BH0C, BL0C, BH1C, BL1C, BH0N, BL0N, BH1N, BL1N) \
  {                                                                               \
    const int t_j = (TJ);                                                         \
    const int jb = (t_j + 1 < NT) ? t_j + 1 : 0;                                  \
    const size_t tb = (size_t)(jt + 2 * jb + ks) * 8192;                          \
    BH0N = *reinterpret_cast<const bf16x8*>(Th + tb + bo0);                       \
    BL0N = *reinterpret_cast<const bf16x8*>(Tl + tb + bo0);                       \
    BH1N = *reinterpret_cast<const bf16x8*>(Th + tb + bo0 + 4096);                \
    BL1N = *reinterpret_cast<const bf16x8*>(Tl + tb + bo0 + 4096);                \
    float e0 = (svrA + NVC.x) * MCA.x; e0 = fmaxf(e0, 0.2f * e0); e0 = fminf(e0, 70.f); \
    float e1 = (svrA + NVC.y) * MCA.y; e1 = fmaxf(e1, 0.2f * e1); e1 = fminf(e1, 70.f); \
    float e2 = (svrB + NVC.x) * MCB.x; e2 = fmaxf(e2, 0.2f * e2); e2 = fminf(e2, 70.f); \
    float e3 = (svrB + NVC.y) * MCB.y; e3 = fmaxf(e3, 0.2f * e3); e3 = fminf(e3, 70.f); \
    const float pA0 = ((MKA >> (2 * (p2 & 15))) & 1u) ? __expf(e0) : 0.f;         \
    const float pA1 = ((MKA >> (2 * (p2 & 15) + 1)) & 1u) ? __expf(e1) : 0.f;     \
    const float pB0 = ((MKB >> (2 * (p2 & 15))) & 1u) ? __expf(e2) : 0.f;         \
    const float pB1 = ((MKB >> (2 * (p2 & 15) + 1)) & 1u) ? __expf(e3) : 0.f;     \
    rsumA += pA0 + pA1; rsumB += pB0 + pB1;                                       \
    const int jm = (t_j + 2 < NT) ? t_j + 2 : 0;                                  \
    MCA = *reinterpret_cast<const float2*>(&Mm[mrowA + (size_t)jm * 64 + 2 * p2]); \
    MKA = mkrowA[jm * 2 + (p2 >> 4)];                                             \
    MCB = *reinterpret_cast<const float2*>(&Mm[mrowB + (size_t)jm * 64 + 2 * p2]); \
    MKB = mkrowB[jm * 2 + (p2 >> 4)];                                             \
    NVC = *reinterpret_cast<const float2*>(&nvs[jm * 64 + 2 * p2]);               \
    const uint hwA = cvt_pk_bf16(pA0, pA1);                                       \
    const uint lwA = cvt_pk_bf16(pA0 - __uint_as_float(hwA << 16),                \
                                 pA1 - __uint_as_float(hwA & 0xffff0000u));       \
    const uint hwB = cvt_pk_bf16(pB0, pB1);                                       \
    const uint lwB = cvt_pk_bf16(pB0 - __uint_as_float(hwB << 16),                \
                                 pB1 - __uint_as_float(hwB & 0xffff0000u));       \
    Pa[t_j & 1][0][0][pidx] = hwA;                                                \
    Pa[t_j & 1][1][0][pidx] = lwA;                                                \
    Pa[t_j & 1][0][1][pidx] = hwB;                                                \
    Pa[t_j & 1][1][1][pidx] = lwB;                                                \
    lds_barrier();                                                                \
    const bf16x8 ahA0 = *reinterpret_cast<const bf16x8*>(&Pa[t_j & 1][0][0][aidx]);       \
    const bf16x8 alA0 = *reinterpret_cast<const bf16x8*>(&Pa[t_j & 1][1][0][aidx]);       \
    const bf16x8 ahA1 = *reinterpret_cast<const bf16x8*>(&Pa[t_j & 1][0][0][aidx + 264]); \
    const bf16x8 alA1 = *reinterpret_cast<const bf16x8*>(&Pa[t_j & 1][1][0][aidx + 264]); \
    const bf16x8 ahB0 = *reinterpret_cast<const bf16x8*>(&Pa[t_j & 1][0][1][aidx]);       \
    const bf16x8 alB0 = *reinterpret_cast<const bf16x8*>(&Pa[t_j & 1][1][1][aidx]);       \
    const bf16x8 ahB1 = *reinterpret_cast<const bf16x8*>(&Pa[t_j & 1][0][1][aidx + 264]); \
    const bf16x8 alB1 = *reinterpret_cast<const bf16x8*>(&Pa[t_j & 1][1][1][aidx + 264]); \
    accA = __builtin_amdgcn_mfma_f32_32x32x16_bf16(alA0, BH0C, accA, 0, 0, 0);    \
    accB = __builtin_amdgcn_mfma_f32_32x32x16_bf16(alB0, BH0C, accB, 0, 0, 0);    \
    accA = __builtin_amdgcn_mfma_f32_32x32x16_bf16(ahA0, BL0C, accA, 0, 0, 0);    \
    accB = __builtin_amdgcn_mfma_f32_32x32x16_bf16(ahB0, BL0C, accB, 0, 0, 0);    \
    accA = __builtin_amdgcn_mfma_f32_32x32x16_bf16(ahA0, BH0C, accA, 0, 0, 0);    \
    accB = __builtin_amdgcn_mfma_f32_32x32x16_bf16(ahB0, BH0C, accB, 0, 0, 0);    \
    accA = __builtin_amdgcn_mfma_f32_32x32x16_bf16(alA1, BH1C, accA, 0, 0, 0);    \
    accB = __builtin_amdgcn_mfma_f32_32x32x16_bf16(alB1, BH1C, accB, 0, 0, 0);    \
    accA = __builtin_amdgcn_mfma_f32_32x32x16_bf16(ahA1, BL1C, accA, 0, 0, 0);    \
    accB = __builtin_amdgcn_mfma_f32_32x32x16_bf16(ahB1, BL1C, accB, 0, 0, 0);    \
    accA = __builtin_amdgcn_mfma_f32_32x32x16_bf16(ahA1, BH1C, accA, 0, 0, 0);    \
    accB = __builtin_amdgcn_mfma_f32_32x32x16_bf16(ahB1, BH1C, accB, 0, 0, 0);    \
  }

  for (int tj = 0; tj < NT; tj += 2) {
    STEP1(tj,     MA_e, mkA_e, MB_e, mkB_e, nv_e, bh0_e, bl0_e, bh1_e, bl1_e, bh0_o, bl0_o, bh1_o, bl1_o)
    STEP1(tj + 1, MA_o, mkA_o, MB_o, mkB_o, nv_o, bh0_o, bl0_o, bh1_o, bl1_o, bh0_e, bl0_e, bh1_e, bl1_e)
  }
#undef STEP1

  #pragma unroll
  for (int off = 1; off < 32; off <<= 1) {
    rsumA += __shfl_xor(rsumA, off);
    rsumB += __shfl_xor(rsumB, off);
  }
  if (p2 == 0) { l_lds[r] = rsumA; l_lds[32 + r] = rsumB; }
  __syncthreads();
  if (t < 64) pL[(size_t)jh * 8192 + i0 + t] = l_lds[t];

  // k-half reduce via LDS scratch (reuse nvs, 32KB), rowgroup A then B.
  float* scratch = nvs;
  if (ks == 1) {
    #pragma unroll
    for (int reg = 0; reg < 16; ++reg) scratch[cf * 1024 + reg * 64 + lane] = accA[reg];
  }
  __syncthreads();
  if (ks == 0) {
    #pragma unroll
    for (int reg = 0; reg < 16; ++reg) {
      const int row = (reg & 3) + 8 * (reg >> 2) + 4 * (lane >> 5);
      pO[(size_t)jh * 8192 * F + (size_t)(i0 + row) * F + col] =
          accA[reg] + scratch[cf * 1024 + reg * 64 + lane];
    }
  }
  __syncthreads();
  if (ks == 1) {
    #pragma unroll
    for (int reg = 0; reg < 16; ++reg) scratch[cf * 1024 + reg * 64 + lane] = accB[reg];
  }
  __syncthreads();
  if (ks == 0) {
    #pragma unroll
    for (int reg = 0; reg < 16; ++reg) {
      const int row = (reg & 3) + 8 * (reg >> 2) + 4 * (lane >> 5);
      pO[(size_t)jh * 8192 * F + (size_t)(i0 + 32 + row) * F + col] =
          accB[reg] + scratch[cf * 1024 + reg * 64 + lane];
    }
  }
}

// ---------------------------------------------------------------------------
// Layer-2 fused attention. Grid (128,2): 64 rows x j-half, 1024 thr.
// Wave w: rb = w&1 (16-row frag), cf = (w>>1)&3 (16-col frag), ks = w>>3.
// Per STEP: 6 MFMAs (2 rowgroups x bf16x3), B loaded once. Partial outputs.
// ---------------------------------------------------------------------------
__global__ __launch_bounds__(1024, 4) void attn2_kernel(
    const float* __restrict__ Mm, const uint* __restrict__ Bm,
    const float* __restrict__ sv, const float* __restrict__ nv,
    const unsigned short* __restrict__ Th, const unsigned short* __restrict__ Tl,
    float* __restrict__ pO, float* __restrict__ pL) {
  constexpr int F = 64, NT = 4096 / 64;
  __shared__ __align__(16) uint Pa[2][2][2][8 * 132];
  __shared__ __align__(16) float nvs[4096];
  __shared__ float l_lds[64];

  const int t = threadIdx.x;
  const int lane = t & 63;
  const int w = t >> 6;
  const int rb = w & 1;
  const int cf = (w >> 1) & 3;
  const int ks = w >> 3;
  const int r = t >> 5;
  const int p2 = t & 31;
  const int i0 = blockIdx.x * 64;
  const int jh = blockIdx.y;
  const size_t jbase = (size_t)jh * 4096;
  const int jt = jh * 128;

  reinterpret_cast<float4*>(nvs)[t] = reinterpret_cast<const float4*>(nv + jbase)[t];

  const float svrA = sv[i0 + r];
  const float svrB = sv[i0 + 32 + r];
  const size_t mrowA = (size_t)(i0 + r) * NN + jbase;
  const size_t mrowB = mrowA + (size_t)32 * NN;
  const uint* mkrowA = Bm + (size_t)(i0 + r) * (NN / 32) + jh * 128;
  const uint* mkrowB = mkrowA + (size_t)32 * (NN / 32);
  const int col = cf * 16 + (lane & 15);
  const size_t bo2 = ((size_t)(lane >> 4) * F + col) * 8;
  const int pidx = (p2 >> 2) * 132 + r * 4 + (p2 & 3);
  const int aidx = (ks * 4 + (lane >> 4)) * 132 + (rb * 16 + (lane & 15)) * 4;

  float2 MA_e = *reinterpret_cast<const float2*>(&Mm[mrowA + 2 * p2]);
  float2 MA_o = *reinterpret_cast<const float2*>(&Mm[mrowA + 64 + 2 * p2]);
  float2 MB_e = *reinterpret_cast<const float2*>(&Mm[mrowB + 2 * p2]);
  float2 MB_o = *reinterpret_cast<const float2*>(&Mm[mrowB + 64 + 2 * p2]);
  uint mkA_e = mkrowA[p2 >> 4];
  uint mkA_o = mkrowA[2 + (p2 >> 4)];
  uint mkB_e = mkrowB[p2 >> 4];
  uint mkB_o = mkrowB[2 + (p2 >> 4)];
  const size_t tb0 = (size_t)(jt + ks) * 2048;
  bf16x8 bh_e = *reinterpret_cast<const bf16x8*>(Th + tb0 + bo2);
  bf16x8 bl_e = *reinterpret_cast<const bf16x8*>(Tl + tb0 + bo2);
  bf16x8 bh_o, bl_o;

  float rsumA = 0.f, rsumB = 0.f;
  f32x4 accA = {0.f, 0.f, 0.f, 0.f}, accA2 = {0.f, 0.f, 0.f, 0.f};
  f32x4 accB = {0.f, 0.f, 0.f, 0.f}, accB2 = {0.f, 0.f, 0.f, 0.f};

  __syncthreads();   // nvs staged

  float2 nv_e = *reinterpret_cast<const float2*>(&nvs[2 * p2]);
  float2 nv_o = *reinterpret_cast<const float2*>(&nvs[64 + 2 * p2]);

#define STEP2(TJ, MCA, MKA, MCB, MKB, NVC, BHC, BLC, BHN, BLN)                    \
  {                                                                               \
    const int t_j = (TJ);                                                         \
    const int jb = (t_j + 1 < NT) ? t_j + 1 : 0;                                  \
    const size_t tb = (size_t)(jt + 2 * jb + ks) * 2048;                          \
    BHN = *reinterpret_cast<const bf16x8*>(Th + tb + bo2);                        \
    BLN = *reinterpret_cast<const bf16x8*>(Tl + tb + bo2);                        \
    float e0 = (svrA + NVC.x) * MCA.x; e0 = fmaxf(e0, 0.2f * e0); e0 = fminf(e0, 70.f); \
    float e1 = (svrA + NVC.y) * MCA.y; e1 = fmaxf(e1, 0.2f * e1); e1 = fminf(e1, 70.f); \
    float e2 = (svrB + NVC.x) * MCB.x; e2 = fmaxf(e2, 0.2f * e2); e2 = fminf(e2, 70.f); \
    float e3 = (svrB + NVC.y) * MCB.y; e3 = fmaxf(e3, 0.2f * e3); e3 = fminf(e3, 70.f); \
    const float pA0 = ((MKA >> (2 * (p2 & 15))) & 1u) ? __expf(e0) : 0.f;         \
    const float pA1 = ((MKA >> (2 * (p2 & 15) + 1)) & 1u) ? __expf(e1) : 0.f;     \
    const float pB0 = ((MKB >> (2 * (p2 & 15))) & 1u) ? __expf(e2) : 0.f;         \
    const float pB1 = ((MKB >> (2 * (p2 & 15) + 1)) & 1u) ? __expf(e3) : 0.f;     \
    rsumA += pA0 + pA1; rsumB += pB0 + pB1;                                       \
    const int jm = (t_j + 2 < NT) ? t_j + 2 : 0;                                  \
    MCA = *reinterpret_cast<const float2*>(&Mm[mrowA + (size_t)jm * 64 + 2 * p2]); \
    MKA = mkrowA[jm * 2 + (p2 >> 4)];                                             \
    MCB = *reinterpret_cast<const float2*>(&Mm[mrowB + (size_t)jm * 64 + 2 * p2]); \
    MKB = mkrowB[jm * 2 + (p2 >> 4)];                                             \
    NVC = *reinterpret_cast<const float2*>(&nvs[jm * 64 + 2 * p2]);               \
    const uint hwA = cvt_pk_bf16(pA0, pA1);                                       \
    const uint lwA = cvt_pk_bf16(pA0 - __uint_as_float(hwA << 16),                \
                                 pA1 - __uint_as_float(hwA & 0xffff0000u));       \
    const uint hwB = cvt_pk_bf16(pB0, pB1);                                       \
    const uint lwB = cvt_pk_bf16(pB0 - __uint_as_float(hwB << 16),                \
                                 pB1 - __uint_as_float(hwB & 0xffff0000u));       \
    Pa[t_j & 1][0][0][pidx] = hwA;                                                \
    Pa[t_j & 1][1][0][pidx] = lwA;                                                \
    Pa[t_j & 1][0][1][pidx] = hwB;                                                \
    Pa[t_j & 1][1][1][pidx] = lwB;                                                \
    lds_barrier();                                                                \
    const bf16x8 ahA = *reinterpret_cast<const bf16x8*>(&Pa[t_j & 1][0][0][aidx]); \
    const bf16x8 alA = *reinterpret_cast<const bf16x8*>(&Pa[t_j & 1][1][0][aidx]); \
    const bf16x8 ahB = *reinterpret_cast<const bf16x8*>(&Pa[t_j & 1][0][1][aidx]); \
    const bf16x8 alB = *reinterpret_cast<const bf16x8*>(&Pa[t_j & 1][1][1][aidx]); \
    accA  = __builtin_amdgcn_mfma_f32_16x16x32_bf16(alA, BHC, accA, 0, 0, 0);     \
    accB  = __builtin_amdgcn_mfma_f32_16x16x32_bf16(alB, BHC, accB, 0, 0, 0);     \
    accA2 = __builtin_amdgcn_mfma_f32_16x16x32_bf16(ahA, BLC, accA2, 0, 0, 0);    \
    accB2 = __builtin_amdgcn_mfma_f32_16x16x32_bf16(ahB, BLC, accB2, 0, 0, 0);    \
    accA  = __builtin_amdgcn_mfma_f32_16x16x32_bf16(ahA, BHC, accA, 0, 0, 0);     \
    accB  = __builtin_amdgcn_mfma_f32_16x16x32_bf16(ahB, BHC, accB, 0, 0, 0);     \
  }

  for (int tj = 0; tj < NT; tj += 2) {
    STEP2(tj,     MA_e, mkA_e, MB_e, mkB_e, nv_e, bh_e, bl_e, bh_o, bl_o)
    STEP2(tj + 1, MA_o, mkA_o, MB_o, mkB_o, nv_o, bh_o, bl_o, bh_e, bl_e)
  }
#undef STEP2

  #pragma unroll
  for (int off = 1; off < 32; off <<= 1) {
    rsumA += __shfl_xor(rsumA, off);
    rsumB += __shfl_xor(rsumB, off);
  }
  if (p2 == 0) { l_lds[r] = rsumA; l_lds[32 + r] = rsumB; }
  __syncthreads();
  if (t < 64) pL[(size_t)jh * 8192 + i0 + t] = l_lds[t];

  float* scratch = nvs;
  if (ks == 1) {
    #pragma unroll
    for (int reg = 0; reg < 4; ++reg)
      scratch[(w & 7) * 256 + reg * 64 + lane] = accA[reg] + accA2[reg];
  }
  __syncthreads();
  if (ks == 0) {
    #pragma unroll
    for (int reg = 0; reg < 4; ++reg) {
      const int row = rb * 16 + (lane >> 4) * 4 + reg;
      pO[(size_t)jh * 8192 * F + (size_t)(i0 + row) * F + col] =
          accA[reg] + accA2[reg] + scratch[(w & 7) * 256 + reg * 64 + lane];
    }
  }
  __syncthreads();
  if (ks == 1) {
    #pragma unroll
    for (int reg = 0; reg < 4; ++reg)
      scratch[(w & 7) * 256 + reg * 64 + lane] = accB[reg] + accB2[reg];
  }
  __syncthreads();
  if (ks == 0) {
    #pragma unroll
    for (int reg = 0; reg < 4; ++reg) {
      const int row = rb * 16 + (lane >> 4) * 4 + reg;
      pO[(size_t)jh * 8192 * F + (size_t)(i0 + 32 + row) * F + col] =
          accB[reg] + accB2[reg] + scratch[(w & 7) * 256 + reg * 64 + lane];
    }
  }
}

// ---------------------------------------------------------------------------
extern "C" void kernel_launch(void* const* d_in, const int* in_sizes, int n_in,
                              void* d_out, int out_size, void* d_ws, size_t ws_size,
                              hipStream_t stream) {
  const float* x   = (const float*)d_in[0];
  const int*   adj = (const int*)  d_in[1];
  const float* Mm  = (const float*)d_in[2];
  const float* W0  = (const float*)d_in[3];
  const float* as0 = (const float*)d_in[4];
  const float* an0 = (const float*)d_in[5];
  const float* W1  = (const float*)d_in[6];
  const float* as1 = (const float*)d_in[7];
  const float* an1 = (const float*)d_in[8];
  float* out = (float*)d_out;

  char* ws = (char*)d_ws;
  const size_t MB = 1048576;
  const size_t KB = 1024;
  float* h0  = (float*)(ws);                              // 8 MB (dead after split1)
  uint*  Bm  = (uint*) (ws);                              // 8 MB (written after split1)
  float* x1  = (float*)(ws + 8 * MB);                     // 8 MB
  float* h1  = (float*)(ws + 16 * MB);                    // 2 MB
  unsigned short* Th0 = (unsigned short*)(ws + 18 * MB);  // 4 MB
  unsigned short* Tl0 = (unsigned short*)(ws + 22 * MB);  // 4 MB
  unsigned short* Th1 = (unsigned short*)(ws + 26 * MB);  // 1 MB
  unsigned short* Tl1 = (unsigned short*)(ws + 27 * MB);  // 1 MB
  float* s0  = (float*)(ws + 28 * MB);
  float* n0  = (float*)(ws + 28 * MB + 32 * KB);
  float* s1  = (float*)(ws + 28 * MB + 64 * KB);
  float* n1  = (float*)(ws + 28 * MB + 96 * KB);
  float* pL1 = (float*)(ws + 28 * MB + 128 * KB);         // 64 KB [2][8192]
  float* pL2 = (float*)(ws + 28 * MB + 192 * KB);         // 64 KB
  float* pO1 = (float*)(ws + 29 * MB);                    // 16 MB [2][8192][256]
  float* pO2 = (float*)(ws + 29 * MB);                    // 4 MB  [2][8192][64] (pO1 dead by then)

  // ---- layer 1 ----
  gemm_kernel<512, 256><<<dim3(128, 4), dim3(256), 0, stream>>>(x, W0, h0);
  sn_kernel<256><<<dim3(2048), dim3(256), 0, stream>>>(h0, as0, an0, s0, n0);
  split_kernel<256><<<dim3(256), dim3(256), 0, stream>>>(h0, Th0, Tl0);
  mask_kernel<<<dim3(65536), dim3(256), 0, stream>>>(adj, Bm);   // h0 now dead
  attn1_kernel<<<dim3(128, 2), dim3(1024), 0, stream>>>(Mm, Bm, s0, n0, Th0, Tl0, pO1, pL1);
  combine_kernel<256><<<dim3(2048), dim3(256), 0, stream>>>(pO1, pL1, x1);
  // ---- layer 2 ----
  gemm_kernel<256, 64><<<dim3(128, 1), dim3(256), 0, stream>>>(x1, W1, h1);
  sn_kernel<64><<<dim3(2048), dim3(256), 0, stream>>>(h1, as1, an1, s1, n1);
  split_kernel<64><<<dim3(256), dim3(256), 0, stream>>>(h1, Th1, Tl1);
  attn2_kernel<<<dim3(128, 2), dim3(1024), 0, stream>>>(Mm, Bm, s1, n1, Th1, Tl1, pO2, pL2);
  combine_kernel<64><<<dim3(512), dim3(256), 0, stream>>>(pO2, pL2, out);
}

// Round 15
// 329.448 us; speedup vs baseline: 2.2979x; 1.0227x over previous
//
#include <hip/hip_runtime.h>
#include <hip/hip_bf16.h>

constexpr int NN = 8192;
using uint = unsigned int;

typedef __bf16 bf16x8 __attribute__((ext_vector_type(8)));
typedef float f32x4 __attribute__((ext_vector_type(4)));
typedef float f32x16 __attribute__((ext_vector_type(16)));
typedef unsigned short ushort8_t __attribute__((ext_vector_type(8)));

__device__ __forceinline__ float eluf(float z) { return z > 0.f ? z : __expf(z) - 1.f; }

__device__ __forceinline__ unsigned short bf16_hi(float v) {
  unsigned u = __float_as_uint(v);
  unsigned r = u + 0x7fffu + ((u >> 16) & 1u);
  return (unsigned short)(r >> 16);
}
__device__ __forceinline__ float bf16_tof(unsigned short u) {
  return __uint_as_float(((unsigned)u) << 16);
}

__device__ __forceinline__ uint cvt_pk_bf16(float a, float b) {
  uint r;
  asm("v_cvt_pk_bf16_f32 %0, %1, %2" : "=v"(r) : "v"(a), "v"(b));
  return r;
}

// LDS-only barrier: order LDS ops across the barrier WITHOUT draining vmcnt.
__device__ __forceinline__ void lds_barrier() {
  asm volatile("s_waitcnt lgkmcnt(0)" ::: "memory");
  __builtin_amdgcn_s_barrier();
}

// ---------------------------------------------------------------------------
// GEMM: C[M][NOUT] = A[M][K] @ W[K][NOUT]   (fp32, layer-2 only)
// ---------------------------------------------------------------------------
template<int K, int NOUT>
__global__ __launch_bounds__(256) void gemm_kernel(
    const float* __restrict__ A, const float* __restrict__ W, float* __restrict__ C) {
  constexpr int BM = 64, BN = 64, BK = 16;
  __shared__ __align__(16) float As[BK][BM + 4];
  __shared__ __align__(16) float Ws[BK][BN];
  const int t = threadIdx.x;
  const int i0 = blockIdx.x * BM;
  const int c0 = blockIdx.y * BN;
  const int tr = t >> 4;
  const int tc = t & 15;
  const int lr = t >> 2;
  const int lk = (t & 3) * 4;
  const int wk = t >> 4;
  const int wc = (t & 15) * 4;
  float acc[4][4] = {};
  for (int k0 = 0; k0 < K; k0 += BK) {
    const float4 a4 = *reinterpret_cast<const float4*>(&A[(size_t)(i0 + lr) * K + k0 + lk]);
    As[lk + 0][lr] = a4.x; As[lk + 1][lr] = a4.y;
    As[lk + 2][lr] = a4.z; As[lk + 3][lr] = a4.w;
    *reinterpret_cast<float4*>(&Ws[wk][wc]) =
        *reinterpret_cast<const float4*>(&W[(size_t)(k0 + wk) * NOUT + c0 + wc]);
    __syncthreads();
    #pragma unroll
    for (int kk = 0; kk < BK; ++kk) {
      const float4 av = *reinterpret_cast<const float4*>(&As[kk][4 * tr]);
      const float4 wv = *reinterpret_cast<const float4*>(&Ws[kk][4 * tc]);
      const float a[4] = {av.x, av.y, av.z, av.w};
      const float w[4] = {wv.x, wv.y, wv.z, wv.w};
      #pragma unroll
      for (int i = 0; i < 4; ++i)
        #pragma unroll
        for (int j = 0; j < 4; ++j) acc[i][j] += a[i] * w[j];
    }
    __syncthreads();
  }
  #pragma unroll
  for (int i = 0; i < 4; ++i) {
    const float4 o = make_float4(acc[i][0], acc[i][1], acc[i][2], acc[i][3]);
    *reinterpret_cast<float4*>(&C[(size_t)(i0 + 4 * tr + i) * NOUT + c0 + 4 * tc]) = o;
  }
}

// ---------------------------------------------------------------------------
// splitx: x [8192][512] fp32 -> hi/lo bf16 in MFMA A-staging layout:
//   T[(k>>3)*8192 + row]*8 + (k&7).  One thread per (kt=k/32, row): reads one
//   full 128B line of x, writes 4x ushort8 (lane-contiguous 16B stores).
// ---------------------------------------------------------------------------
__global__ __launch_bounds__(256) void splitx_kernel(
    const float* __restrict__ X, unsigned short* __restrict__ Th,
    unsigned short* __restrict__ Tl) {
  const size_t tid = (size_t)blockIdx.x * 256 + threadIdx.x;  // 16*8192
  const int kt = (int)(tid >> 13);
  const int row = (int)(tid & 8191);
  const float* src = X + (size_t)row * 512 + kt * 32;
  #pragma unroll
  for (int kc = 0; kc < 4; ++kc) {
    ushort8_t hi, lo;
    #pragma unroll
    for (int e = 0; e < 8; ++e) {
      const float v = src[kc * 8 + e];
      const unsigned short h = bf16_hi(v);
      hi[e] = h;
      lo[e] = bf16_hi(v - bf16_tof(h));
    }
    const size_t o = ((size_t)(kt * 4 + kc) * 8192 + row) * 8;
    *reinterpret_cast<ushort8_t*>(&Th[o]) = hi;
    *reinterpret_cast<ushort8_t*>(&Tl[o]) = lo;
  }
}

// ---------------------------------------------------------------------------
// splitw: W0 [512][256] fp32 -> hi/lo bf16 in B-staging (Th-like) layout:
//   T[(k>>3)*256 + col]*8 + (k&7).  One thread per (kb=k>>3, col).
// ---------------------------------------------------------------------------
__global__ __launch_bounds__(256) void splitw_kernel(
    const float* __restrict__ W, unsigned short* __restrict__ Th,
    unsigned short* __restrict__ Tl) {
  const int tid = blockIdx.x * 256 + threadIdx.x;   // 64*256
  const int kb = tid >> 8;
  const int col = tid & 255;
  ushort8_t hi, lo;
  #pragma unroll
  for (int e = 0; e < 8; ++e) {
    const float v = W[(size_t)(kb * 8 + e) * 256 + col];
    const unsigned short h = bf16_hi(v);
    hi[e] = h;
    lo[e] = bf16_hi(v - bf16_tof(h));
  }
  const size_t o = ((size_t)kb * 256 + col) * 8;
  *reinterpret_cast<ushort8_t*>(&Th[o]) = hi;
  *reinterpret_cast<ushort8_t*>(&Tl[o]) = lo;
}

// ---------------------------------------------------------------------------
// gemm1_mfma: h0[8192][256] = x @ W0 via bf16x3 MFMA (32x32x16).
// Grid 256 blocks (32 rows each), 512 thr = 8 waves (wave = 32-col frag).
// Fragment maps identical to attn1's verified layouts. Single acc chain
// (~60 VGPR demand, fits the 64-cap without spilling).
// ---------------------------------------------------------------------------
__global__ __launch_bounds__(512) void gemm1_mfma_kernel(
    const unsigned short* __restrict__ Axh, const unsigned short* __restrict__ Axl,
    const unsigned short* __restrict__ Bwh, const unsigned short* __restrict__ Bwl,
    float* __restrict__ C) {
  const int t = threadIdx.x;
  const int lane = t & 63;
  const int cf = t >> 6;
  const int i0 = blockIdx.x * 32;
  const int col = cf * 32 + (lane & 31);
  const size_t abase = ((size_t)(lane >> 5) * 8192 + i0 + (lane & 31)) * 8;
  const size_t bbase = ((size_t)(lane >> 5) * 256 + col) * 8;

  f32x16 acc;
  #pragma unroll
  for (int i = 0; i < 16; ++i) acc[i] = 0.f;

  #pragma unroll 2
  for (int kt = 0; kt < 16; ++kt) {
    const size_t at = (size_t)kt * 4 * 8192 * 8;
    const size_t bt = (size_t)kt * 4 * 256 * 8;
    #pragma unroll
    for (int h = 0; h < 2; ++h) {
      const size_t ao = at + (size_t)h * 2 * 8192 * 8 + abase;
      const size_t bo = bt + (size_t)h * 2 * 256 * 8 + bbase;
      const bf16x8 ah = *reinterpret_cast<const bf16x8*>(Axh + ao);
      const bf16x8 al = *reinterpret_cast<const bf16x8*>(Axl + ao);
      const bf16x8 bh = *reinterpret_cast<const bf16x8*>(Bwh + bo);
      const bf16x8 bl = *reinterpret_cast<const bf16x8*>(Bwl + bo);
      acc = __builtin_amdgcn_mfma_f32_32x32x16_bf16(al, bh, acc, 0, 0, 0);
      acc = __builtin_amdgcn_mfma_f32_32x32x16_bf16(ah, bl, acc, 0, 0, 0);
      acc = __builtin_amdgcn_mfma_f32_32x32x16_bf16(ah, bh, acc, 0, 0, 0);
    }
  }

  #pragma unroll
  for (int reg = 0; reg < 16; ++reg) {
    const int row = (reg & 3) + 8 * (reg >> 2) + 4 * (lane >> 5);
    C[(size_t)(i0 + row) * 256 + col] = acc[reg];
  }
}

// ---------------------------------------------------------------------------
// s[i] = h[i].a_self ; n[i] = h[i].a_neigh   (one wave per row)
// ---------------------------------------------------------------------------
template<int FOUT>
__global__ __launch_bounds__(256) void sn_kernel(
    const float* __restrict__ H, const float* __restrict__ a_self,
    const float* __restrict__ a_neigh, float* __restrict__ s, float* __restrict__ n) {
  const int wave = threadIdx.x >> 6;
  const int lane = threadIdx.x & 63;
  const int row = blockIdx.x * 4 + wave;
  float ds = 0.f, dn = 0.f;
  #pragma unroll
  for (int c = lane; c < FOUT; c += 64) {
    const float h = H[(size_t)row * FOUT + c];
    ds += h * a_self[c];
    dn += h * a_neigh[c];
  }
  #pragma unroll
  for (int off = 32; off > 0; off >>= 1) {
    ds += __shfl_down(ds, off);
    dn += __shfl_down(dn, off);
  }
  if (lane == 0) { s[row] = ds; n[row] = dn; }
}

// ---------------------------------------------------------------------------
// Split H (fp32 [N][F]) into hi/lo bf16 in MFMA-staging layout:
//   T[tile=j/32][kc8=0..3][col=0..F-1][e=0..7]  (element j = tile*32+kc8*8+e)
// ---------------------------------------------------------------------------
template<int F>
__global__ __launch_bounds__(256) void split_kernel(
    const float* __restrict__ H, unsigned short* __restrict__ Th,
    unsigned short* __restrict__ Tl) {
  const int t = threadIdx.x;
  const int tile = blockIdx.x;
  const int c = t & (F - 1);
  const int kcb = t / F;
  for (int kc = kcb; kc < 4; kc += 256 / F) {
    ushort8_t hi, lo;
    #pragma unroll
    for (int e = 0; e < 8; ++e) {
      float v = H[(size_t)(tile * 32 + kc * 8 + e) * F + c];
      unsigned short h = bf16_hi(v);
      hi[e] = h;
      lo[e] = bf16_hi(v - bf16_tof(h));
    }
    size_t o = ((size_t)(tile * 4 + kc) * F + c) * 8;
    *reinterpret_cast<ushort8_t*>(&Th[o]) = hi;
    *reinterpret_cast<ushort8_t*>(&Tl[o]) = lo;
  }
}

// ---------------------------------------------------------------------------
// adj (int32 0/1) -> bitmask, word W covers cols [W*32, W*32+32) of a row.
// ---------------------------------------------------------------------------
__global__ __launch_bounds__(256) void mask_kernel(
    const int* __restrict__ adj, uint* __restrict__ Bm) {
  const size_t tg = (size_t)blockIdx.x * 256 + threadIdx.x;
  const int4 a = *reinterpret_cast<const int4*>(&adj[tg * 4]);
  uint nib = (a.x > 0 ? 1u : 0u) | (a.y > 0 ? 2u : 0u) |
             (a.z > 0 ? 4u : 0u) | (a.w > 0 ? 8u : 0u);
  const int lane = threadIdx.x & 63;
  uint v = nib << ((lane & 7) * 4);
  v |= __shfl_xor(v, 1);
  v |= __shfl_xor(v, 2);
  v |= __shfl_xor(v, 4);
  if ((lane & 7) == 0) Bm[tg >> 3] = v;
}

// ---------------------------------------------------------------------------
// combine: out = elu((pO[0]+pO[1]) / (pL[0]+pL[1]))   (j-half partial merge)
// ---------------------------------------------------------------------------
template<int F>
__global__ __launch_bounds__(256) void combine_kernel(
    const float* __restrict__ pO, const float* __restrict__ pL, float* __restrict__ out) {
  const size_t q = (size_t)blockIdx.x * 256 + threadIdx.x;
  const size_t base = q * 4;
  const int row = (int)(base / F);
  const float4 a = *reinterpret_cast<const float4*>(pO + base);
  const float4 b = *reinterpret_cast<const float4*>(pO + (size_t)8192 * F + base);
  const float il = 1.0f / (pL[row] + pL[8192 + row]);
  float4 o;
  o.x = eluf((a.x + b.x) * il);
  o.y = eluf((a.y + b.y) * il);
  o.z = eluf((a.z + b.z) * il);
  o.w = eluf((a.w + b.w) * il);
  *reinterpret_cast<float4*>(out + base) = o;
}

// ---------------------------------------------------------------------------
// Layer-1 fused attention. Grid (128,2): block = 64 rows (2 rowgroups) x j-half.
// 1024 thr (16 waves): cf = w&7 (32-col frag), ks = w>>3 (k-half of 64-tile).
// Per STEP: scores for both rowgroups (4/thread), B-frags loaded ONCE and
// reused by both rowgroups' MFMAs (12 MFMAs, 2 chains). Partial out + rowsum.
// ---------------------------------------------------------------------------
__global__ __launch_bounds__(1024, 4) void attn1_kernel(
    const float* __restrict__ Mm, const uint* __restrict__ Bm,
    const float* __restrict__ sv, const float* __restrict__ nv,
    const unsigned short* __restrict__ Th, const unsigned short* __restrict__ Tl,
    float* __restrict__ pO, float* __restrict__ pL) {
  constexpr int F = 256, NT = 4096 / 64;
  __shared__ __align__(16) uint Pa[2][2][2][8 * 132];  // [buf][part][rg][g*132+r*4+q]
  __shared__ __align__(16) float nvs[8192];            // [0..4095]=nv half; full=scratch
  __shared__ float l_lds[64];

  const int t = threadIdx.x;
  const int lane = t & 63;
  const int w = t >> 6;
  const int cf = w & 7;
  const int ks = w >> 3;
  const int r = t >> 5;              // score row 0..31 (per rowgroup)
  const int p2 = t & 31;             // col pair 2p2,2p2+1 (of 64)
  const int i0 = blockIdx.x * 64;
  const int jh = blockIdx.y;
  const size_t jbase = (size_t)jh * 4096;
  const int jt = jh * 128;           // tile32 base

  reinterpret_cast<float4*>(nvs)[t] = reinterpret_cast<const float4*>(nv + jbase)[t];

  const float svrA = sv[i0 + r];
  const float svrB = sv[i0 + 32 + r];
  const size_t mrowA = (size_t)(i0 + r) * NN + jbase;
  const size_t mrowB = mrowA + (size_t)32 * NN;
  const uint* mkrowA = Bm + (size_t)(i0 + r) * (NN / 32) + jh * 128;
  const uint* mkrowB = mkrowA + (size_t)32 * (NN / 32);
  const int col = cf * 32 + (lane & 31);
  const size_t bo0 = ((size_t)(lane >> 5) * F + col) * 8;
  const int pidx = (p2 >> 2) * 132 + r * 4 + (p2 & 3);
  const int aidx = (ks * 4 + (lane >> 5)) * 132 + (lane & 31) * 4;

  float2 MA_e = *reinterpret_cast<const float2*>(&Mm[mrowA + 2 * p2]);
  float2 MA_o = *reinterpret_cast<const float2*>(&Mm[mrowA + 64 + 2 * p2]);
  float2 MB_e = *reinterpret_cast<const float2*>(&Mm[mrowB + 2 * p2]);
  float2 MB_o = *reinterpret_cast<const float2*>(&Mm[mrowB + 64 + 2 * p2]);
  uint mkA_e = mkrowA[p2 >> 4];
  uint mkA_o = mkrowA[2 + (p2 >> 4)];
  uint mkB_e = mkrowB[p2 >> 4];
  uint mkB_o = mkrowB[2 + (p2 >> 4)];
  const size_t tb0 = (size_t)(jt + ks) * 8192;
  bf16x8 bh0_e = *reinterpret_cast<const bf16x8*>(Th + tb0 + bo0);
  bf16x8 bl0_e = *reinterpret_cast<const bf16x8*>(Tl + tb0 + bo0);
  bf16x8 bh1_e = *reinterpret_cast<const bf16x8*>(Th + tb0 + bo0 + 4096);
  bf16x8 bl1_e = *reinterpret_cast<const bf16x8*>(Tl + tb0 + bo0 + 4096);
  bf16x8 bh0_o, bl0_o, bh1_o, bl1_o;

  float rsumA = 0.f, rsumB = 0.f;
  f32x16 accA, accB;
  #pragma unroll
  for (int i = 0; i < 16; ++i) { accA[i] = 0.f; accB[i] = 0.f; }

  __syncthreads();   // nvs staged

  float2 nv_e = *reinterpret_cast<const float2*>(&nvs[2 * p2]);
  float2 nv_o = *reinterpret_cast<const float2*>(&nvs[64 + 2 * p2]);

#define STEP1(TJ, MCA, MKA, MCB, MKB, NVC, BH0C, BL0C, BH1C, BL1C, BH0N, BL0N, BH1N, BL1N) \
  {                                                                               \
    const int t_j = (TJ);                                                         \
    const int jb = (t_j + 1 < NT) ? t_j + 1 : 0;                                  \
    const size_t tb = (size_t)(jt + 2 * jb + ks) * 8192;                          \
    BH0N = *reinterpret_cast<const bf16x8*>(Th + tb + bo0);                       \
    BL0N = *reinterpret_cast<const bf16x8*>(Tl + tb + bo0);                       \
    BH1N = *reinterpret_cast<const bf16x8*>(Th + tb + bo0 + 4096);                \
    BL1N = *reinterpret_cast<const bf16x8*>(Tl + tb + bo0 + 4096);                \
    float e0 = (svrA + NVC.x) * MCA.x; e0 = fmaxf(e0, 0.2f * e0); e0 = fminf(e0, 70.f); \
    float e1 = (svrA + NVC.y) * MCA.y; e1 = fmaxf(e1, 0.2f * e1); e1 = fminf(e1, 70.f); \
    float e2 = (svrB + NVC.x) * MCB.x; e2 = fmaxf(e2, 0.2f * e2); e2 = fminf(e2, 70.f); \
    float e3 = (svrB + NVC.y) * MCB.y; e3 = fmaxf(e3, 0.2f * e3); e3 = fminf(e3, 70.f); \
    const float pA0 = ((MKA >> (2 * (p2 & 15))) & 1u) ? __expf(e0) : 0.f;         \
    const float pA1 = ((MKA >> (2 * (p2 & 15) + 1)) & 1u) ? __expf(e1) : 0.f;     \
    const float pB0 = ((MKB >> (2 * (p2 & 15))) & 1u) ? __expf(e2) : 0.f;         \
    const float pB1 = ((MKB >> (2 * (p2 & 15) + 1)) & 1u) ? __expf(e3) : 0.f;     \
    rsumA += pA0 + pA1; rsumB += pB0 + pB1;                                       \
    const int jm = (t_j + 2 < NT) ? t_j + 2 : 0;                                  \
    MCA = *reinterpret_cast<const float2*>(&Mm[mrowA + (size_t)jm * 64 + 2 * p2]); \
    MKA = mkrowA[jm * 2 + (p2 >> 4)];                                             \
    MCB = *reinterpret_cast<const float2*>(&Mm[mrowB + (size_t)jm * 64 + 2 * p2]); \
    MKB = mkrowB[jm * 2 + (p2 >> 4)];                                             \
    NVC = *reinterpret_cast<const float2*>(&nvs[jm * 64 + 2 * p2]);               \
    const uint hwA = cvt_pk_bf16(pA0, pA1);                                       \
    const uint lwA = cvt_pk_bf16(pA0 - __uint_as_float(hwA << 16),                \
                                 pA1 - __uint_as_float(hwA & 0xffff0000u));       \
    const uint hwB = cvt_pk_bf16(pB0, pB1);                                       \
    const uint lwB = cvt_pk_bf16(pB0 - __uint_as_float(hwB << 16),                \
                                 pB1 - __uint_as_float(hwB & 0xffff0000u));       \
    Pa[t_j & 1][0][0][pidx] = hwA;                                                \
    Pa[t_j & 1][1][0][pidx] = lwA;                                                \
    Pa[t_j & 1][0][1][pidx] = hwB;                                                \
    Pa[t_j & 1][1][1][pidx] = lwB;                                                \
    lds_barrier();                                                                \
    const bf16x8 ahA0 = *reinterpret_cast<const bf16x8*>(&Pa[t_j & 1][0][0][aidx]);       \
    const bf16x8 alA0 = *reinterpret_cast<const bf16x8*>(&Pa[t_j & 1][1][0][aidx]);       \
    const bf16x8 ahA1 = *reinterpret_cast<const bf16x8*>(&Pa[t_j & 1][0][0][aidx + 264]); \
    const bf16x8 alA1 = *reinterpret_cast<const bf16x8*>(&Pa[t_j & 1][1][0][aidx + 264]); \
    const bf16x8 ahB0 = *reinterpret_cast<const bf16x8*>(&Pa[t_j & 1][0][1][aidx]);       \
    const bf16x8 alB0 = *reinterpret_cast<const bf16x8*>(&Pa[t_j & 1][1][1][aidx]);       \
    const bf16x8 ahB1 = *reinterpret_cast<const bf16x8*>(&Pa[t_j & 1][0][1][aidx + 264]); \
    const bf16x8 alB1 = *reinterpret_cast<const bf16x8*>(&Pa[t_j & 1][1][1][aidx + 264]); \
    accA = __builtin_amdgcn_mfma_f32_32x32x16_bf16(alA0, BH0C, accA, 0, 0, 0);    \
    accB = __builtin_amdgcn_mfma_f32_32x32x16_bf16(alB0, BH0C, accB, 0, 0, 0);    \
    accA = __builtin_amdgcn_mfma_f32_32x32x16_bf16(ahA0, BL0C, accA, 0, 0, 0);    \
    accB = __builtin_amdgcn_mfma_f32_32x32x16_bf16(ahB0, BL0C, accB, 0, 0, 0);    \
    accA = __builtin_amdgcn_mfma_f32_32x32x16_bf16(ahA0, BH0C, accA, 0, 0, 0);    \
    accB = __builtin_amdgcn_mfma_f32_32x32x16_bf16(ahB0, BH0C, accB, 0, 0, 0);    \
    accA = __builtin_amdgcn_mfma_f32_32x32x16_bf16(alA1, BH1C, accA, 0, 0, 0);    \
    accB = __builtin_amdgcn_mfma_f32_32x32x16_bf16(alB1, BH1C, accB, 0, 0, 0);    \
    accA = __builtin_amdgcn_mfma_f32_32x32x16_bf16(ahA1, BL1C, accA, 0, 0, 0);    \
    accB = __builtin_amdgcn_mfma_f32_32x32x16_bf16(ahB1, BL1C, accB, 0, 0, 0);    \
    accA = __builtin_amdgcn_mfma_f32_32x32x16_bf16(ahA1, BH1C, accA, 0, 0, 0);    \
    accB = __builtin_amdgcn_mfma_f32_32x32x16_bf16(ahB1, BH1C, accB, 0, 0, 0);    \
  }

  for (int tj = 0; tj < NT; tj += 2) {
    STEP1(tj,     MA_e, mkA_e, MB_e, mkB_e, nv_e, bh0_e, bl0_e, bh1_e, bl1_e, bh0_o, bl0_o, bh1_o, bl1_o)
    STEP1(tj + 1, MA_o, mkA_o, MB_o, mkB_o, nv_o, bh0_o, bl0_o, bh1_o, bl1_o, bh0_e, bl0_e, bh1_e, bl1_e)
  }
#undef STEP1

  #pragma unroll
  for (int off = 1; off < 32; off <<= 1) {
    rsumA += __shfl_xor(rsumA, off);
    rsumB += __shfl_xor(rsumB, off);
  }
  if (p2 == 0) { l_lds[r] = rsumA; l_lds[32 + r] = rsumB; }
  __syncthreads();
  if (t < 64) pL[(size_t)jh * 8192 + i0 + t] = l_lds[t];

  // k-half reduce via LDS scratch (reuse nvs, 32KB), rowgroup A then B.
  float* scratch = nvs;
  if (ks == 1) {
    #pragma unroll
    for (int reg = 0; reg < 16; ++reg) scratch[cf * 1024 + reg * 64 + lane] = accA[reg];
  }
  __syncthreads();
  if (ks == 0) {
    #pragma unroll
    for (int reg = 0; reg < 16; ++reg) {
      const int row = (reg & 3) + 8 * (reg >> 2) + 4 * (lane >> 5);
      pO[(size_t)jh * 8192 * F + (size_t)(i0 + row) * F + col] =
          accA[reg] + scratch[cf * 1024 + reg * 64 + lane];
    }
  }
  __syncthreads();
  if (ks == 1) {
    #pragma unroll
    for (int reg = 0; reg < 16; ++reg) scratch[cf * 1024 + reg * 64 + lane] = accB[reg];
  }
  __syncthreads();
  if (ks == 0) {
    #pragma unroll
    for (int reg = 0; reg < 16; ++reg) {
      const int row = (reg & 3) + 8 * (reg >> 2) + 4 * (lane >> 5);
      pO[(size_t)jh * 8192 * F + (size_t)(i0 + 32 + row) * F + col] =
          accB[reg] + scratch[cf * 1024 + reg * 64 + lane];
    }
  }
}

// ---------------------------------------------------------------------------
// Layer-2 fused attention. Grid (128,2): 64 rows x j-half, 1024 thr.
// Wave w: rb = w&1 (16-row frag), cf = (w>>1)&3 (16-col frag), ks = w>>3.
// Per STEP: 6 MFMAs (2 rowgroups x bf16x3), B loaded once. Partial outputs.
// ---------------------------------------------------------------------------
__global__ __launch_bounds__(1024, 4) void attn2_kernel(
    const float* __restrict__ Mm, const uint* __restrict__ Bm,
    const float* __restrict__ sv, const float* __restrict__ nv,
    const unsigned short* __restrict__ Th, const unsigned short* __restrict__ Tl,
    float* __restrict__ pO, float* __restrict__ pL) {
  constexpr int F = 64, NT = 4096 / 64;
  __shared__ __align__(16) uint Pa[2][2][2][8 * 132];
  __shared__ __align__(16) float nvs[4096];
  __shared__ float l_lds[64];

  const int t = threadIdx.x;
  const int lane = t & 63;
  const int w = t >> 6;
  const int rb = w & 1;
  const int cf = (w >> 1) & 3;
  const int ks = w >> 3;
  const int r = t >> 5;
  const int p2 = t & 31;
  const int i0 = blockIdx.x * 64;
  const int jh = blockIdx.y;
  const size_t jbase = (size_t)jh * 4096;
  const int jt = jh * 128;

  reinterpret_cast<float4*>(nvs)[t] = reinterpret_cast<const float4*>(nv + jbase)[t];

  const float svrA = sv[i0 + r];
  const float svrB = sv[i0 + 32 + r];
  const size_t mrowA = (size_t)(i0 + r) * NN + jbase;
  const size_t mrowB = mrowA + (size_t)32 * NN;
  const uint* mkrowA = Bm + (size_t)(i0 + r) * (NN / 32) + jh * 128;
  const uint* mkrowB = mkrowA + (size_t)32 * (NN / 32);
  const int col = cf * 16 + (lane & 15);
  const size_t bo2 = ((size_t)(lane >> 4) * F + col) * 8;
  const int pidx = (p2 >> 2) * 132 + r * 4 + (p2 & 3);
  const int aidx = (ks * 4 + (lane >> 4)) * 132 + (rb * 16 + (lane & 15)) * 4;

  float2 MA_e = *reinterpret_cast<const float2*>(&Mm[mrowA + 2 * p2]);
  float2 MA_o = *reinterpret_cast<const float2*>(&Mm[mrowA + 64 + 2 * p2]);
  float2 MB_e = *reinterpret_cast<const float2*>(&Mm[mrowB + 2 * p2]);
  float2 MB_o = *reinterpret_cast<const float2*>(&Mm[mrowB + 64 + 2 * p2]);
  uint mkA_e = mkrowA[p2 >> 4];
  uint mkA_o = mkrowA[2 + (p2 >> 4)];
  uint mkB_e = mkrowB[p2 >> 4];
  uint mkB_o = mkrowB[2 + (p2 >> 4)];
  const size_t tb0 = (size_t)(jt + ks) * 2048;
  bf16x8 bh_e = *reinterpret_cast<const bf16x8*>(Th + tb0 + bo2);
  bf16x8 bl_e = *reinterpret_cast<const bf16x8*>(Tl + tb0 + bo2);
  bf16x8 bh_o, bl_o;

  float rsumA = 0.f, rsumB = 0.f;
  f32x4 accA = {0.f, 0.f, 0.f, 0.f}, accA2 = {0.f, 0.f, 0.f, 0.f};
  f32x4 accB = {0.f, 0.f, 0.f, 0.f}, accB2 = {0.f, 0.f, 0.f, 0.f};

  __syncthreads();   // nvs staged

  float2 nv_e = *reinterpret_cast<const float2*>(&nvs[2 * p2]);
  float2 nv_o = *reinterpret_cast<const float2*>(&nvs[64 + 2 * p2]);

#define STEP2(TJ, MCA, MKA, MCB, MKB, NVC, BHC, BLC, BHN, BLN)                    \
  {                                                                               \
    const int t_j = (TJ);                                                         \
    const int jb = (t_j + 1 < NT) ? t_j + 1 : 0;                                  \
    const size_t tb = (size_t)(jt + 2 * jb + ks) * 2048;                          \
    BHN = *reinterpret_cast<const bf16x8*>(Th + tb + bo2);                        \
    BLN = *reinterpret_cast<const bf16x8*>(Tl + tb + bo2);                        \
    float e0 = (svrA + NVC.x) * MCA.x; e0 = fmaxf(e0, 0.2f * e0); e0 = fminf(e0, 70.f); \
    float e1 = (svrA + NVC.y) * MCA.y; e1 = fmaxf(e1, 0.2f * e1); e1 = fminf(e1, 70.f); \
    float e2 = (svrB + NVC.x) * MCB.x; e2 = fmaxf(e2, 0.2f * e2); e2 = fminf(e2, 70.f); \
    float e3 = (svrB + NVC.y) * MCB.y; e3 = fmaxf(e3, 0.2f * e3); e3 = fminf(e3, 70.f); \
    const float pA0 = ((MKA >> (2 * (p2 & 15))) & 1u) ? __expf(e0) : 0.f;         \
    const float pA1 = ((MKA >> (2 * (p2 & 15) + 1)) & 1u) ? __expf(e1) : 0.f;     \
    const float pB0 = ((MKB >> (2 * (p2 & 15))) & 1u) ? __expf(e2) : 0.f;         \
    const float pB1 = ((MKB >> (2 * (p2 & 15) + 1)) & 1u) ? __expf(e3) : 0.f;     \
    rsumA += pA0 + pA1; rsumB += pB0 + pB1;                                       \
    const int jm = (t_j + 2 < NT) ? t_j + 2 : 0;                                  \
    MCA = *reinterpret_cast<const float2*>(&Mm[mrowA + (size_t)jm * 64 + 2 * p2]); \
    MKA = mkrowA[jm * 2 + (p2 >> 4)];                                             \
    MCB = *reinterpret_cast<const float2*>(&Mm[mrowB + (size_t)jm * 64 + 2 * p2]); \
    MKB = mkrowB[jm * 2 + (p2 >> 4)];                                             \
    NVC = *reinterpret_cast<const float2*>(&nvs[jm * 64 + 2 * p2]);               \
    const uint hwA = cvt_pk_bf16(pA0, pA1);                                       \
    const uint lwA = cvt_pk_bf16(pA0 - __uint_as_float(hwA << 16),                \
                                 pA1 - __uint_as_float(hwA & 0xffff0000u));       \
    const uint hwB = cvt_pk_bf16(pB0, pB1);                                       \
    const uint lwB = cvt_pk_bf16(pB0 - __uint_as_float(hwB << 16),                \
                                 pB1 - __uint_as_float(hwB & 0xffff0000u));       \
    Pa[t_j & 1][0][0][pidx] = hwA;                                                \
    Pa[t_j & 1][1][0][pidx] = lwA;                                                \
    Pa[t_j & 1][0][1][pidx] = hwB;                                                \
    Pa[t_j & 1][1][1][pidx] = lwB;                                                \
    lds_barrier();                                                                \
    const bf16x8 ahA = *reinterpret_cast<const bf16x8*>(&Pa[t_j & 1][0][0][aidx]); \
    const bf16x8 alA = *reinterpret_cast<const bf16x8*>(&Pa[t_j & 1][1][0][aidx]); \
    const bf16x8 ahB = *reinterpret_cast<const bf16x8*>(&Pa[t_j & 1][0][1][aidx]); \
    const bf16x8 alB = *reinterpret_cast<const bf16x8*>(&Pa[t_j & 1][1][1][aidx]); \
    accA  = __builtin_amdgcn_mfma_f32_16x16x32_bf16(alA, BHC, accA, 0, 0, 0);     \
    accB  = __builtin_amdgcn_mfma_f32_16x16x32_bf16(alB, BHC, accB, 0, 0, 0);     \
    accA2 = __builtin_amdgcn_mfma_f32_16x16x32_bf16(ahA, BLC, accA2, 0, 0, 0);    \
    accB2 = __builtin_amdgcn_mfma_f32_16x16x32_bf16(ahB, BLC, accB2, 0, 0, 0);    \
    accA  = __builtin_amdgcn_mfma_f32_16x16x32_bf16(ahA, BHC, accA, 0, 0, 0);     \
    accB  = __builtin_amdgcn_mfma_f32_16x16x32_bf16(ahB, BHC, accB, 0, 0, 0);     \
  }

  for (int tj = 0; tj < NT; tj += 2) {
    STEP2(tj,     MA_e, mkA_e, MB_e, mkB_e, nv_e, bh_e, bl_e, bh_o, bl_o)
    STEP2(tj + 1, MA_o, mkA_o, MB_o, mkB_o, nv_o, bh_o, bl_o, bh_e, bl_e)
  }
#undef STEP2

  #pragma unroll
  for (int off = 1; off < 32; off <<= 1) {
    rsumA += __shfl_xor(rsumA, off);
    rsumB += __shfl_xor(rsumB, off);
  }
  if (p2 == 0) { l_lds[r] = rsumA; l_lds[32 + r] = rsumB; }
  __syncthreads();
  if (t < 64) pL[(size_t)jh * 8192 + i0 + t] = l_lds[t];

  float* scratch = nvs;
  if (ks == 1) {
    #pragma unroll
    for (int reg = 0; reg < 4; ++reg)
      scratch[(w & 7) * 256 + reg * 64 + lane] = accA[reg] + accA2[reg];
  }
  __syncthreads();
  if (ks == 0) {
    #pragma unroll
    for (int reg = 0; reg < 4; ++reg) {
      const int row = rb * 16 + (lane >> 4) * 4 + reg;
      pO[(size_t)jh * 8192 * F + (size_t)(i0 + row) * F + col] =
          accA[reg] + accA2[reg] + scratch[(w & 7) * 256 + reg * 64 + lane];
    }
  }
  __syncthreads();
  if (ks == 1) {
    #pragma unroll
    for (int reg = 0; reg < 4; ++reg)
      scratch[(w & 7) * 256 + reg * 64 + lane] = accB[reg] + accB2[reg];
  }
  __syncthreads();
  if (ks == 0) {
    #pragma unroll
    for (int reg = 0; reg < 4; ++reg) {
      const int row = rb * 16 + (lane >> 4) * 4 + reg;
      pO[(size_t)jh * 8192 * F + (size_t)(i0 + 32 + row) * F + col] =
          accB[reg] + accB2[reg] + scratch[(w & 7) * 256 + reg * 64 + lane];
    }
  }
}

// ---------------------------------------------------------------------------
extern "C" void kernel_launch(void* const* d_in, const int* in_sizes, int n_in,
                              void* d_out, int out_size, void* d_ws, size_t ws_size,
                              hipStream_t stream) {
  const float* x   = (const float*)d_in[0];
  const int*   adj = (const int*)  d_in[1];
  const float* Mm  = (const float*)d_in[2];
  const float* W0  = (const float*)d_in[3];
  const float* as0 = (const float*)d_in[4];
  const float* an0 = (const float*)d_in[5];
  const float* W1  = (const float*)d_in[6];
  const float* as1 = (const float*)d_in[7];
  const float* an1 = (const float*)d_in[8];
  float* out = (float*)d_out;

  char* ws = (char*)d_ws;
  const size_t MB = 1048576;
  const size_t KB = 1024;
  float* h0  = (float*)(ws);                              // 8 MB (dead after split1)
  uint*  Bm  = (uint*) (ws);                              // 8 MB (written after split1)
  float* x1  = (float*)(ws + 8 * MB);                     // 8 MB
  float* h1  = (float*)(ws + 16 * MB);                    // 2 MB
  unsigned short* Th0 = (unsigned short*)(ws + 18 * MB);  // 4 MB
  unsigned short* Tl0 = (unsigned short*)(ws + 22 * MB);  // 4 MB
  unsigned short* Th1 = (unsigned short*)(ws + 26 * MB);  // 1 MB
  unsigned short* Tl1 = (unsigned short*)(ws + 27 * MB);  // 1 MB
  float* s0  = (float*)(ws + 28 * MB);
  float* n0  = (float*)(ws + 28 * MB + 32 * KB);
  float* s1  = (float*)(ws + 28 * MB + 64 * KB);
  float* n1  = (float*)(ws + 28 * MB + 96 * KB);
  float* pL1 = (float*)(ws + 28 * MB + 128 * KB);         // 64 KB [2][8192]
  float* pL2 = (float*)(ws + 28 * MB + 192 * KB);         // 64 KB
  float* pO1 = (float*)(ws + 29 * MB);                    // 16 MB [2][8192][256]
  float* pO2 = (float*)(ws + 29 * MB);                    // 4 MB  [2][8192][64] (pO1 dead by then)
  unsigned short* Txh = (unsigned short*)(ws + 64 * MB);  // 8 MB (x split hi)
  unsigned short* Txl = (unsigned short*)(ws + 72 * MB);  // 8 MB (x split lo)
  unsigned short* Twh = (unsigned short*)(ws + 80 * MB);  // 256 KB (W0 split hi)
  unsigned short* Twl = (unsigned short*)(ws + 81 * MB);  // 256 KB (W0 split lo)

  // ---- layer 1 ----
  splitx_kernel<<<dim3(512), dim3(256), 0, stream>>>(x, Txh, Txl);
  splitw_kernel<<<dim3(64), dim3(256), 0, stream>>>(W0, Twh, Twl);
  gemm1_mfma_kernel<<<dim3(256), dim3(512), 0, stream>>>(Txh, Txl, Twh, Twl, h0);
  sn_kernel<256><<<dim3(2048), dim3(256), 0, stream>>>(h0, as0, an0, s0, n0);
  split_kernel<256><<<dim3(256), dim3(256), 0, stream>>>(h0, Th0, Tl0);
  mask_kernel<<<dim3(65536), dim3(256), 0, stream>>>(adj, Bm);   // h0 now dead
  attn1_kernel<<<dim3(128, 2), dim3(1024), 0, stream>>>(Mm, Bm, s0, n0, Th0, Tl0, pO1, pL1);
  combine_kernel<256><<<dim3(2048), dim3(256), 0, stream>>>(pO1, pL1, x1);
  // ---- layer 2 ----
  gemm_kernel<256, 64><<<dim3(128, 1), dim3(256), 0, stream>>>(x1, W1, h1);
  sn_kernel<64><<<dim3(2048), dim3(256), 0, stream>>>(h1, as1, an1, s1, n1);
  split_kernel<64><<<dim3(256), dim3(256), 0, stream>>>(h1, Th1, Tl1);
  attn2_kernel<<<dim3(128, 2), dim3(1024), 0, stream>>>(Mm, Bm, s1, n1, Th1, Tl1, pO2, pL2);
  combine_kernel<64><<<dim3(512), dim3(256), 0, stream>>>(pO2, pL2, out);
}

// Round 16
// 325.028 us; speedup vs baseline: 2.3292x; 1.0136x over previous
//
#include <hip/hip_runtime.h>
#include <hip/hip_bf16.h>

constexpr int NN = 8192;
using uint = unsigned int;

typedef __bf16 bf16x8 __attribute__((ext_vector_type(8)));
typedef float f32x4 __attribute__((ext_vector_type(4)));
typedef float f32x16 __attribute__((ext_vector_type(16)));
typedef unsigned short ushort8_t __attribute__((ext_vector_type(8)));

__device__ __forceinline__ float eluf(float z) { return z > 0.f ? z : __expf(z) - 1.f; }

__device__ __forceinline__ unsigned short bf16_hi(float v) {
  unsigned u = __float_as_uint(v);
  unsigned r = u + 0x7fffu + ((u >> 16) & 1u);
  return (unsigned short)(r >> 16);
}
__device__ __forceinline__ float bf16_tof(unsigned short u) {
  return __uint_as_float(((unsigned)u) << 16);
}

__device__ __forceinline__ uint cvt_pk_bf16(float a, float b) {
  uint r;
  asm("v_cvt_pk_bf16_f32 %0, %1, %2" : "=v"(r) : "v"(a), "v"(b));
  return r;
}

// LDS-only barrier: order LDS ops across the barrier WITHOUT draining vmcnt.
__device__ __forceinline__ void lds_barrier() {
  asm volatile("s_waitcnt lgkmcnt(0)" ::: "memory");
  __builtin_amdgcn_s_barrier();
}

// ---------------------------------------------------------------------------
// splitx: x [8192][512] fp32 -> hi/lo bf16 in MFMA A-staging layout.
// ---------------------------------------------------------------------------
__global__ __launch_bounds__(256) void splitx_kernel(
    const float* __restrict__ X, unsigned short* __restrict__ Th,
    unsigned short* __restrict__ Tl) {
  const size_t tid = (size_t)blockIdx.x * 256 + threadIdx.x;  // 16*8192
  const int kt = (int)(tid >> 13);
  const int row = (int)(tid & 8191);
  const float* src = X + (size_t)row * 512 + kt * 32;
  #pragma unroll
  for (int kc = 0; kc < 4; ++kc) {
    ushort8_t hi, lo;
    #pragma unroll
    for (int e = 0; e < 8; ++e) {
      const float v = src[kc * 8 + e];
      const unsigned short h = bf16_hi(v);
      hi[e] = h;
      lo[e] = bf16_hi(v - bf16_tof(h));
    }
    const size_t o = ((size_t)(kt * 4 + kc) * 8192 + row) * 8;
    *reinterpret_cast<ushort8_t*>(&Th[o]) = hi;
    *reinterpret_cast<ushort8_t*>(&Tl[o]) = lo;
  }
}

// ---------------------------------------------------------------------------
// splitw: W0 [512][256] fp32 -> hi/lo bf16 in B-staging layout.
// ---------------------------------------------------------------------------
__global__ __launch_bounds__(256) void splitw_kernel(
    const float* __restrict__ W, unsigned short* __restrict__ Th,
    unsigned short* __restrict__ Tl) {
  const int tid = blockIdx.x * 256 + threadIdx.x;   // 64*256
  const int kb = tid >> 8;
  const int col = tid & 255;
  ushort8_t hi, lo;
  #pragma unroll
  for (int e = 0; e < 8; ++e) {
    const float v = W[(size_t)(kb * 8 + e) * 256 + col];
    const unsigned short h = bf16_hi(v);
    hi[e] = h;
    lo[e] = bf16_hi(v - bf16_tof(h));
  }
  const size_t o = ((size_t)kb * 256 + col) * 8;
  *reinterpret_cast<ushort8_t*>(&Th[o]) = hi;
  *reinterpret_cast<ushort8_t*>(&Tl[o]) = lo;
}

// ---------------------------------------------------------------------------
// gemm1_mfma: h0 = x @ W0 via bf16x3 MFMA (32x32x16), 256 blocks x 512 thr.
// Epilogue FUSES split1: writes h0 (for sn1) AND Th0/Tl0 in split layout.
// ---------------------------------------------------------------------------
__global__ __launch_bounds__(512) void gemm1_mfma_kernel(
    const unsigned short* __restrict__ Axh, const unsigned short* __restrict__ Axl,
    const unsigned short* __restrict__ Bwh, const unsigned short* __restrict__ Bwl,
    float* __restrict__ C, unsigned short* __restrict__ Th,
    unsigned short* __restrict__ Tl) {
  const int t = threadIdx.x;
  const int lane = t & 63;
  const int cf = t >> 6;
  const int i0 = blockIdx.x * 32;
  const int col = cf * 32 + (lane & 31);
  const size_t abase = ((size_t)(lane >> 5) * 8192 + i0 + (lane & 31)) * 8;
  const size_t bbase = ((size_t)(lane >> 5) * 256 + col) * 8;

  f32x16 acc;
  #pragma unroll
  for (int i = 0; i < 16; ++i) acc[i] = 0.f;

  #pragma unroll 2
  for (int kt = 0; kt < 16; ++kt) {
    const size_t at = (size_t)kt * 4 * 8192 * 8;
    const size_t bt = (size_t)kt * 4 * 256 * 8;
    #pragma unroll
    for (int h = 0; h < 2; ++h) {
      const size_t ao = at + (size_t)h * 2 * 8192 * 8 + abase;
      const size_t bo = bt + (size_t)h * 2 * 256 * 8 + bbase;
      const bf16x8 ah = *reinterpret_cast<const bf16x8*>(Axh + ao);
      const bf16x8 al = *reinterpret_cast<const bf16x8*>(Axl + ao);
      const bf16x8 bh = *reinterpret_cast<const bf16x8*>(Bwh + bo);
      const bf16x8 bl = *reinterpret_cast<const bf16x8*>(Bwl + bo);
      acc = __builtin_amdgcn_mfma_f32_32x32x16_bf16(al, bh, acc, 0, 0, 0);
      acc = __builtin_amdgcn_mfma_f32_32x32x16_bf16(ah, bl, acc, 0, 0, 0);
      acc = __builtin_amdgcn_mfma_f32_32x32x16_bf16(ah, bh, acc, 0, 0, 0);
    }
  }

  #pragma unroll
  for (int reg = 0; reg < 16; ++reg) {
    const int row = (reg & 3) + 8 * (reg >> 2) + 4 * (lane >> 5);
    const float v = acc[reg];
    C[(size_t)(i0 + row) * 256 + col] = v;
    // fused split1: row within tile = kc*8+e
    const unsigned short h = bf16_hi(v);
    const unsigned short l = bf16_hi(v - bf16_tof(h));
    const size_t o = ((size_t)(blockIdx.x * 4 + (row >> 3)) * 256 + col) * 8 + (row & 7);
    Th[o] = h;
    Tl[o] = l;
  }
}

// ---------------------------------------------------------------------------
// s[i] = h[i].a_self ; n[i] = h[i].a_neigh   (one wave per row) — layer 1
// ---------------------------------------------------------------------------
template<int FOUT>
__global__ __launch_bounds__(256) void sn_kernel(
    const float* __restrict__ H, const float* __restrict__ a_self,
    const float* __restrict__ a_neigh, float* __restrict__ s, float* __restrict__ n) {
  const int wave = threadIdx.x >> 6;
  const int lane = threadIdx.x & 63;
  const int row = blockIdx.x * 4 + wave;
  float ds = 0.f, dn = 0.f;
  #pragma unroll
  for (int c = lane; c < FOUT; c += 64) {
    const float h = H[(size_t)row * FOUT + c];
    ds += h * a_self[c];
    dn += h * a_neigh[c];
  }
  #pragma unroll
  for (int off = 32; off > 0; off >>= 1) {
    ds += __shfl_down(ds, off);
    dn += __shfl_down(dn, off);
  }
  if (lane == 0) { s[row] = ds; n[row] = dn; }
}

// ---------------------------------------------------------------------------
// adj (int32 0/1) -> bitmask, word W covers cols [W*32, W*32+32) of a row.
// ---------------------------------------------------------------------------
__global__ __launch_bounds__(256) void mask_kernel(
    const int* __restrict__ adj, uint* __restrict__ Bm) {
  const size_t tg = (size_t)blockIdx.x * 256 + threadIdx.x;
  const int4 a = *reinterpret_cast<const int4*>(&adj[tg * 4]);
  uint nib = (a.x > 0 ? 1u : 0u) | (a.y > 0 ? 2u : 0u) |
             (a.z > 0 ? 4u : 0u) | (a.w > 0 ? 8u : 0u);
  const int lane = threadIdx.x & 63;
  uint v = nib << ((lane & 7) * 4);
  v |= __shfl_xor(v, 1);
  v |= __shfl_xor(v, 2);
  v |= __shfl_xor(v, 4);
  if ((lane & 7) == 0) Bm[tg >> 3] = v;
}

// ---------------------------------------------------------------------------
// plsum: il[row] = 1/(pL[0][row] + pL[1][row])
// ---------------------------------------------------------------------------
__global__ __launch_bounds__(256) void plsum_kernel(
    const float* __restrict__ pL, float* __restrict__ il) {
  const int i = blockIdx.x * 256 + threadIdx.x;
  il[i] = 1.0f / (pL[i] + pL[8192 + i]);
}

// ---------------------------------------------------------------------------
// combine2: out = elu((pO[0]+pO[1]) / (pL[0]+pL[1]))   (final output)
// ---------------------------------------------------------------------------
template<int F>
__global__ __launch_bounds__(256) void combine_kernel(
    const float* __restrict__ pO, const float* __restrict__ pL, float* __restrict__ out) {
  const size_t q = (size_t)blockIdx.x * 256 + threadIdx.x;
  const size_t base = q * 4;
  const int row = (int)(base / F);
  const float4 a = *reinterpret_cast<const float4*>(pO + base);
  const float4 b = *reinterpret_cast<const float4*>(pO + (size_t)8192 * F + base);
  const float il = 1.0f / (pL[row] + pL[8192 + row]);
  float4 o;
  o.x = eluf((a.x + b.x) * il);
  o.y = eluf((a.y + b.y) * il);
  o.z = eluf((a.z + b.z) * il);
  o.w = eluf((a.w + b.w) * il);
  *reinterpret_cast<float4*>(out + base) = o;
}

// ---------------------------------------------------------------------------
// gemm2_fused: h1 = elu((pO1_0+pO1_1)*il1) @ W1, with combine applied in the
// A-staging (x1 never materialized) and the epilogue fusing sn2 + split2
// (h1 never materialized). Grid (128), 256 thr, BM=64, BN=64(=full F), BK=16.
// ---------------------------------------------------------------------------
__global__ __launch_bounds__(256) void gemm2_fused_kernel(
    const float* __restrict__ pO1, const float* __restrict__ il1,
    const float* __restrict__ W, const float* __restrict__ a_self,
    const float* __restrict__ a_neigh, unsigned short* __restrict__ Th,
    unsigned short* __restrict__ Tl, float* __restrict__ s1,
    float* __restrict__ n1) {
  constexpr int K = 256, NOUT = 64, BM = 64, BK = 16;
  const size_t seg = (size_t)8192 * 256;
  __shared__ __align__(16) float As[BK][BM + 4];
  __shared__ __align__(16) float Ws[BK][NOUT];
  __shared__ float red_s[64][17];
  __shared__ float red_n[64][17];
  const int t = threadIdx.x;
  const int i0 = blockIdx.x * BM;
  const int tr = t >> 4;
  const int tc = t & 15;
  const int lr = t >> 2;
  const int lk = (t & 3) * 4;
  const int wk = t >> 4;
  const int wc = (t & 15) * 4;
  const float ilr = il1[i0 + lr];
  float acc[4][4] = {};
  for (int k0 = 0; k0 < K; k0 += BK) {
    // fused combine1: a = elu((p0+p1)*il)
    const size_t aoff = (size_t)(i0 + lr) * 256 + k0 + lk;
    const float4 p0 = *reinterpret_cast<const float4*>(&pO1[aoff]);
    const float4 p1 = *reinterpret_cast<const float4*>(&pO1[seg + aoff]);
    As[lk + 0][lr] = eluf((p0.x + p1.x) * ilr);
    As[lk + 1][lr] = eluf((p0.y + p1.y) * ilr);
    As[lk + 2][lr] = eluf((p0.z + p1.z) * ilr);
    As[lk + 3][lr] = eluf((p0.w + p1.w) * ilr);
    *reinterpret_cast<float4*>(&Ws[wk][wc]) =
        *reinterpret_cast<const float4*>(&W[(size_t)(k0 + wk) * NOUT + wc]);
    __syncthreads();
    #pragma unroll
    for (int kk = 0; kk < BK; ++kk) {
      const float4 av = *reinterpret_cast<const float4*>(&As[kk][4 * tr]);
      const float4 wv = *reinterpret_cast<const float4*>(&Ws[kk][4 * tc]);
      const float a[4] = {av.x, av.y, av.z, av.w};
      const float w[4] = {wv.x, wv.y, wv.z, wv.w};
      #pragma unroll
      for (int i = 0; i < 4; ++i)
        #pragma unroll
        for (int j = 0; j < 4; ++j) acc[i][j] += a[i] * w[j];
    }
    __syncthreads();
  }
  // fused sn2: partial dots over this thread's 4 cols, reduce via LDS
  float asv[4], anv[4];
  #pragma unroll
  for (int j = 0; j < 4; ++j) {
    asv[j] = a_self[4 * tc + j];
    anv[j] = a_neigh[4 * tc + j];
  }
  #pragma unroll
  for (int i = 0; i < 4; ++i) {
    float ps = 0.f, pn = 0.f;
    #pragma unroll
    for (int j = 0; j < 4; ++j) { ps += acc[i][j] * asv[j]; pn += acc[i][j] * anv[j]; }
    red_s[4 * tr + i][tc] = ps;
    red_n[4 * tr + i][tc] = pn;
  }
  // fused split2: Th1/Tl1 in split layout (tile = global_row/32)
  #pragma unroll
  for (int i = 0; i < 4; ++i) {
    const int row = 4 * tr + i;
    const int tile = 2 * blockIdx.x + (row >> 5);
    const int kc = (row >> 3) & 3;
    const int e = row & 7;
    #pragma unroll
    for (int j = 0; j < 4; ++j) {
      const int col = 4 * tc + j;
      const float v = acc[i][j];
      const unsigned short h = bf16_hi(v);
      const unsigned short l = bf16_hi(v - bf16_tof(h));
      const size_t o = ((size_t)(tile * 4 + kc) * 64 + col) * 8 + e;
      Th[o] = h;
      Tl[o] = l;
    }
  }
  __syncthreads();
  if (t < 64) {
    float ss = 0.f, nn = 0.f;
    #pragma unroll
    for (int q = 0; q < 16; ++q) { ss += red_s[t][q]; nn += red_n[t][q]; }
    s1[i0 + t] = ss;
    n1[i0 + t] = nn;
  }
}

// ---------------------------------------------------------------------------
// Layer-1 fused attention. Grid (128,2): block = 64 rows (2 rowgroups) x j-half.
// ---------------------------------------------------------------------------
__global__ __launch_bounds__(1024, 4) void attn1_kernel(
    const float* __restrict__ Mm, const uint* __restrict__ Bm,
    const float* __restrict__ sv, const float* __restrict__ nv,
    const unsigned short* __restrict__ Th, const unsigned short* __restrict__ Tl,
    float* __restrict__ pO, float* __restrict__ pL) {
  constexpr int F = 256, NT = 4096 / 64;
  __shared__ __align__(16) uint Pa[2][2][2][8 * 132];  // [buf][part][rg][g*132+r*4+q]
  __shared__ __align__(16) float nvs[8192];            // [0..4095]=nv half; full=scratch
  __shared__ float l_lds[64];

  const int t = threadIdx.x;
  const int lane = t & 63;
  const int w = t >> 6;
  const int cf = w & 7;
  const int ks = w >> 3;
  const int r = t >> 5;              // score row 0..31 (per rowgroup)
  const int p2 = t & 31;             // col pair 2p2,2p2+1 (of 64)
  const int i0 = blockIdx.x * 64;
  const int jh = blockIdx.y;
  const size_t jbase = (size_t)jh * 4096;
  const int jt = jh * 128;           // tile32 base

  reinterpret_cast<float4*>(nvs)[t] = reinterpret_cast<const float4*>(nv + jbase)[t];

  const float svrA = sv[i0 + r];
  const float svrB = sv[i0 + 32 + r];
  const size_t mrowA = (size_t)(i0 + r) * NN + jbase;
  const size_t mrowB = mrowA + (size_t)32 * NN;
  const uint* mkrowA = Bm + (size_t)(i0 + r) * (NN / 32) + jh * 128;
  const uint* mkrowB = mkrowA + (size_t)32 * (NN / 32);
  const int col = cf * 32 + (lane & 31);
  const size_t bo0 = ((size_t)(lane >> 5) * F + col) * 8;
  const int pidx = (p2 >> 2) * 132 + r * 4 + (p2 & 3);
  const int aidx = (ks * 4 + (lane >> 5)) * 132 + (lane & 31) * 4;

  float2 MA_e = *reinterpret_cast<const float2*>(&Mm[mrowA + 2 * p2]);
  float2 MA_o = *reinterpret_cast<const float2*>(&Mm[mrowA + 64 + 2 * p2]);
  float2 MB_e = *reinterpret_cast<const float2*>(&Mm[mrowB + 2 * p2]);
  float2 MB_o = *reinterpret_cast<const float2*>(&Mm[mrowB + 64 + 2 * p2]);
  uint mkA_e = mkrowA[p2 >> 4];
  uint mkA_o = mkrowA[2 + (p2 >> 4)];
  uint mkB_e = mkrowB[p2 >> 4];
  uint mkB_o = mkrowB[2 + (p2 >> 4)];
  const size_t tb0 = (size_t)(jt + ks) * 8192;
  bf16x8 bh0_e = *reinterpret_cast<const bf16x8*>(Th + tb0 + bo0);
  bf16x8 bl0_e = *reinterpret_cast<const bf16x8*>(Tl + tb0 + bo0);
  bf16x8 bh1_e = *reinterpret_cast<const bf16x8*>(Th + tb0 + bo0 + 4096);
  bf16x8 bl1_e = *reinterpret_cast<const bf16x8*>(Tl + tb0 + bo0 + 4096);
  bf16x8 bh0_o, bl0_o, bh1_o, bl1_o;

  float rsumA = 0.f, rsumB = 0.f;
  f32x16 accA, accB;
  #pragma unroll
  for (int i = 0; i < 16; ++i) { accA[i] = 0.f; accB[i] = 0.f; }

  __syncthreads();   // nvs staged

  float2 nv_e = *reinterpret_cast<const float2*>(&nvs[2 * p2]);
  float2 nv_o = *reinterpret_cast<const float2*>(&nvs[64 + 2 * p2]);

#define STEP1(TJ, MCA, MKA, MCB, MKB, NVC, BH0C, BL0C, BH1C, BL1C, BH0N, BL0N, BH1N, BL1N) \
  {                                                                               \
    const int t_j = (TJ);                                                         \
    const int jb = (t_j + 1 < NT) ? t_j + 1 : 0;                                  \
    const size_t tb = (size_t)(jt + 2 * jb + ks) * 8192;                          \
    BH0N = *reinterpret_cast<const bf16x8*>(Th + tb + bo0);                       \
    BL0N = *reinterpret_cast<const bf16x8*>(Tl + tb + bo0);                       \
    BH1N = *reinterpret_cast<const bf16x8*>(Th + tb + bo0 + 4096);                \
    BL1N = *reinterpret_cast<const bf16x8*>(Tl + tb + bo0 + 4096);                \
    float e0 = (svrA + NVC.x) * MCA.x; e0 = fmaxf(e0, 0.2f * e0); e0 = fminf(e0, 70.f); \
    float e1 = (svrA + NVC.y) * MCA.y; e1 = fmaxf(e1, 0.2f * e1); e1 = fminf(e1, 70.f); \
    float e2 = (svrB + NVC.x) * MCB.x; e2 = fmaxf(e2, 0.2f * e2); e2 = fminf(e2, 70.f); \
    float e3 = (svrB + NVC.y) * MCB.y; e3 = fmaxf(e3, 0.2f * e3); e3 = fminf(e3, 70.f); \
    const float pA0 = ((MKA >> (2 * (p2 & 15))) & 1u) ? __expf(e0) : 0.f;         \
    const float pA1 = ((MKA >> (2 * (p2 & 15) + 1)) & 1u) ? __expf(e1) : 0.f;     \
    const float pB0 = ((MKB >> (2 * (p2 & 15))) & 1u) ? __expf(e2) : 0.f;         \
    const float pB1 = ((MKB >> (2 * (p2 & 15) + 1)) & 1u) ? __expf(e3) : 0.f;     \
    rsumA += pA0 + pA1; rsumB += pB0 + pB1;                                       \
    const int jm = (t_j + 2 < NT) ? t_j + 2 : 0;                                  \
    MCA = *reinterpret_cast<const float2*>(&Mm[mrowA + (size_t)jm * 64 + 2 * p2]); \
    MKA = mkrowA[jm * 2 + (p2 >> 4)];                                             \
    MCB = *reinterpret_cast<const float2*>(&Mm[mrowB + (size_t)jm * 64 + 2 * p2]); \
    MKB = mkrowB[jm * 2 + (p2 >> 4)];                                             \
    NVC = *reinterpret_cast<const float2*>(&nvs[jm * 64 + 2 * p2]);               \
    const uint hwA = cvt_pk_bf16(pA0, pA1);                                       \
    const uint lwA = cvt_pk_bf16(pA0 - __uint_as_float(hwA << 16),                \
                                 pA1 - __uint_as_float(hwA & 0xffff0000u));       \
    const uint hwB = cvt_pk_bf16(pB0, pB1);                                       \
    const uint lwB = cvt_pk_bf16(pB0 - __uint_as_float(hwB << 16),                \
                                 pB1 - __uint_as_float(hwB & 0xffff0000u));       \
    Pa[t_j & 1][0][0][pidx] = hwA;                                                \
    Pa[t_j & 1][1][0][pidx] = lwA;                                                \
    Pa[t_j & 1][0][1][pidx] = hwB;                                                \
    Pa[t_j & 1][1][1][pidx] = lwB;                                                \
    lds_barrier();                                                                \
    const bf16x8 ahA0 = *reinterpret_cast<const bf16x8*>(&Pa[t_j & 1][0][0][aidx]);       \
    const bf16x8 alA0 = *reinterpret_cast<const bf16x8*>(&Pa[t_j & 1][1][0][aidx]);       \
    const bf16x8 ahA1 = *reinterpret_cast<const bf16x8*>(&Pa[t_j & 1][0][0][aidx + 264]); \
    const bf16x8 alA1 = *reinterpret_cast<const bf16x8*>(&Pa[t_j & 1][1][0][aidx + 264]); \
    const bf16x8 ahB0 = *reinterpret_cast<const bf16x8*>(&Pa[t_j & 1][0][1][aidx]);       \
    const bf16x8 alB0 = *reinterpret_cast<const bf16x8*>(&Pa[t_j & 1][1][1][aidx]);       \
    const bf16x8 ahB1 = *reinterpret_cast<const bf16x8*>(&Pa[t_j & 1][0][1][aidx + 264]); \
    const bf16x8 alB1 = *reinterpret_cast<const bf16x8*>(&Pa[t_j & 1][1][1][aidx + 264]); \
    accA = __builtin_amdgcn_mfma_f32_32x32x16_bf16(alA0, BH0C, accA, 0, 0, 0);    \
    accB = __builtin_amdgcn_mfma_f32_32x32x16_bf16(alB0, BH0C, accB, 0, 0, 0);    \
    accA = __builtin_amdgcn_mfma_f32_32x32x16_bf16(ahA0, BL0C, accA, 0, 0, 0);    \
    accB = __builtin_amdgcn_mfma_f32_32x32x16_bf16(ahB0, BL0C, accB, 0, 0, 0);    \
    accA = __builtin_amdgcn_mfma_f32_32x32x16_bf16(ahA0, BH0C, accA, 0, 0, 0);    \
    accB = __builtin_amdgcn_mfma_f32_32x32x16_bf16(ahB0, BH0C, accB, 0, 0, 0);    \
    accA = __builtin_amdgcn_mfma_f32_32x32x16_bf16(alA1, BH1C, accA, 0, 0, 0);    \
    accB = __builtin_amdgcn_mfma_f32_32x32x16_bf16(alB1, BH1C, accB, 0, 0, 0);    \
    accA = __builtin_amdgcn_mfma_f32_32x32x16_bf16(ahA1, BL1C, accA, 0, 0, 0);    \
    accB = __builtin_amdgcn_mfma_f32_32x32x16_bf16(ahB1, BL1C, accB, 0, 0, 0);    \
    accA = __builtin_amdgcn_mfma_f32_32x32x16_bf16(ahA1, BH1C, accA, 0, 0, 0);    \
    accB = __builtin_amdgcn_mfma_f32_32x32x16_bf16(ahB1, BH1C, accB, 0, 0, 0);    \
  }

  for (int tj = 0; tj < NT; tj += 2) {
    STEP1(tj,     MA_e, mkA_e, MB_e, mkB_e, nv_e, bh0_e, bl0_e, bh1_e, bl1_e, bh0_o, bl0_o, bh1_o, bl1_o)
    STEP1(tj + 1, MA_o, mkA_o, MB_o, mkB_o, nv_o, bh0_o, bl0_o, bh1_o, bl1_o, bh0_e, bl0_e, bh1_e, bl1_e)
  }
#undef STEP1

  #pragma unroll
  for (int off = 1; off < 32; off <<= 1) {
    rsumA += __shfl_xor(rsumA, off);
    rsumB += __shfl_xor(rsumB, off);
  }
  if (p2 == 0) { l_lds[r] = rsumA; l_lds[32 + r] = rsumB; }
  __syncthreads();
  if (t < 64) pL[(size_t)jh * 8192 + i0 + t] = l_lds[t];

  // k-half reduce via LDS scratch (reuse nvs, 32KB), rowgroup A then B.
  float* scratch = nvs;
  if (ks == 1) {
    #pragma unroll
    for (int reg = 0; reg < 16; ++reg) scratch[cf * 1024 + reg * 64 + lane] = accA[reg];
  }
  __syncthreads();
  if (ks == 0) {
    #pragma unroll
    for (int reg = 0; reg < 16; ++reg) {
      const int row = (reg & 3) + 8 * (reg >> 2) + 4 * (lane >> 5);
      pO[(size_t)jh * 8192 * F + (size_t)(i0 + row) * F + col] =
          accA[reg] + scratch[cf * 1024 + reg * 64 + lane];
    }
  }
  __syncthreads();
  if (ks == 1) {
    #pragma unroll
    for (int reg = 0; reg < 16; ++reg) scratch[cf * 1024 + reg * 64 + lane] = accB[reg];
  }
  __syncthreads();
  if (ks == 0) {
    #pragma unroll
    for (int reg = 0; reg < 16; ++reg) {
      const int row = (reg & 3) + 8 * (reg >> 2) + 4 * (lane >> 5);
      pO[(size_t)jh * 8192 * F + (size_t)(i0 + 32 + row) * F + col] =
          accB[reg] + scratch[cf * 1024 + reg * 64 + lane];
    }
  }
}

// ---------------------------------------------------------------------------
// Layer-2 fused attention. Grid (128,2): 64 rows x j-half, 1024 thr.
// ---------------------------------------------------------------------------
__global__ __launch_bounds__(1024, 4) void attn2_kernel(
    const float* __restrict__ Mm, const uint* __restrict__ Bm,
    const float* __restrict__ sv, const float* __restrict__ nv,
    const unsigned short* __restrict__ Th, const unsigned short* __restrict__ Tl,
    float* __restrict__ pO, float* __restrict__ pL) {
  constexpr int F = 64, NT = 4096 / 64;
  __shared__ __align__(16) uint Pa[2][2][2][8 * 132];
  __shared__ __align__(16) float nvs[4096];
  __shared__ float l_lds[64];

  const int t = threadIdx.x;
  const int lane = t & 63;
  const int w = t >> 6;
  const int rb = w & 1;
  const int cf = (w >> 1) & 3;
  const int ks = w >> 3;
  const int r = t >> 5;
  const int p2 = t & 31;
  const int i0 = blockIdx.x * 64;
  const int jh = blockIdx.y;
  const size_t jbase = (size_t)jh * 4096;
  const int jt = jh * 128;

  reinterpret_cast<float4*>(nvs)[t] = reinterpret_cast<const float4*>(nv + jbase)[t];

  const float svrA = sv[i0 + r];
  const float svrB = sv[i0 + 32 + r];
  const size_t mrowA = (size_t)(i0 + r) * NN + jbase;
  const size_t mrowB = mrowA + (size_t)32 * NN;
  const uint* mkrowA = Bm + (size_t)(i0 + r) * (NN / 32) + jh * 128;
  const uint* mkrowB = mkrowA + (size_t)32 * (NN / 32);
  const int col = cf * 16 + (lane & 15);
  const size_t bo2 = ((size_t)(lane >> 4) * F + col) * 8;
  const int pidx = (p2 >> 2) * 132 + r * 4 + (p2 & 3);
  const int aidx = (ks * 4 + (lane >> 4)) * 132 + (rb * 16 + (lane & 15)) * 4;

  float2 MA_e = *reinterpret_cast<const float2*>(&Mm[mrowA + 2 * p2]);
  float2 MA_o = *reinterpret_cast<const float2*>(&Mm[mrowA + 64 + 2 * p2]);
  float2 MB_e = *reinterpret_cast<const float2*>(&Mm[mrowB + 2 * p2]);
  float2 MB_o = *reinterpret_cast<const float2*>(&Mm[mrowB + 64 + 2 * p2]);
  uint mkA_e = mkrowA[p2 >> 4];
  uint mkA_o = mkrowA[2 + (p2 >> 4)];
  uint mkB_e = mkrowB[p2 >> 4];
  uint mkB_o = mkrowB[2 + (p2 >> 4)];
  const size_t tb0 = (size_t)(jt + ks) * 2048;
  bf16x8 bh_e = *reinterpret_cast<const bf16x8*>(Th + tb0 + bo2);
  bf16x8 bl_e = *reinterpret_cast<const bf16x8*>(Tl + tb0 + bo2);
  bf16x8 bh_o, bl_o;

  float rsumA = 0.f, rsumB = 0.f;
  f32x4 accA = {0.f, 0.f, 0.f, 0.f}, accA2 = {0.f, 0.f, 0.f, 0.f};
  f32x4 accB = {0.f, 0.f, 0.f, 0.f}, accB2 = {0.f, 0.f, 0.f, 0.f};

  __syncthreads();   // nvs staged

  float2 nv_e = *reinterpret_cast<const float2*>(&nvs[2 * p2]);
  float2 nv_o = *reinterpret_cast<const float2*>(&nvs[64 + 2 * p2]);

#define STEP2(TJ, MCA, MKA, MCB, MKB, NVC, BHC, BLC, BHN, BLN)                    \
  {                                                                               \
    const int t_j = (TJ);                                                         \
    const int jb = (t_j + 1 < NT) ? t_j + 1 : 0;                                  \
    const size_t tb = (size_t)(jt + 2 * jb + ks) * 2048;                          \
    BHN = *reinterpret_cast<const bf16x8*>(Th + tb + bo2);                        \
    BLN = *reinterpret_cast<const bf16x8*>(Tl + tb + bo2);                        \
    float e0 = (svrA + NVC.x) * MCA.x; e0 = fmaxf(e0, 0.2f * e0); e0 = fminf(e0, 70.f); \
    float e1 = (svrA + NVC.y) * MCA.y; e1 = fmaxf(e1, 0.2f * e1); e1 = fminf(e1, 70.f); \
    float e2 = (svrB + NVC.x) * MCB.x; e2 = fmaxf(e2, 0.2f * e2); e2 = fminf(e2, 70.f); \
    float e3 = (svrB + NVC.y) * MCB.y; e3 = fmaxf(e3, 0.2f * e3); e3 = fminf(e3, 70.f); \
    const float pA0 = ((MKA >> (2 * (p2 & 15))) & 1u) ? __expf(e0) : 0.f;         \
    const float pA1 = ((MKA >> (2 * (p2 & 15) + 1)) & 1u) ? __expf(e1) : 0.f;     \
    const float pB0 = ((MKB >> (2 * (p2 & 15))) & 1u) ? __expf(e2) : 0.f;         \
    const float pB1 = ((MKB >> (2 * (p2 & 15) + 1)) & 1u) ? __expf(e3) : 0.f;     \
    rsumA += pA0 + pA1; rsumB += pB0 + pB1;                                       \
    const int jm = (t_j + 2 < NT) ? t_j + 2 : 0;                                  \
    MCA = *reinterpret_cast<const float2*>(&Mm[mrowA + (size_t)jm * 64 + 2 * p2]); \
    MKA = mkrowA[jm * 2 + (p2 >> 4)];                                             \
    MCB = *reinterpret_cast<const float2*>(&Mm[mrowB + (size_t)jm * 64 + 2 * p2]); \
    MKB = mkrowB[jm * 2 + (p2 >> 4)];                                             \
    NVC = *reinterpret_cast<const float2*>(&nvs[jm * 64 + 2 * p2]);               \
    const uint hwA = cvt_pk_bf16(pA0, pA1);                                       \
    const uint lwA = cvt_pk_bf16(pA0 - __uint_as_float(hwA << 16),                \
                                 pA1 - __uint_as_float(hwA & 0xffff0000u));       \
    const uint hwB = cvt_pk_bf16(pB0, pB1);                                       \
    const uint lwB = cvt_pk_bf16(pB0 - __uint_as_float(hwB << 16),                \
                                 pB1 - __uint_as_float(hwB & 0xffff0000u));       \
    Pa[t_j & 1][0][0][pidx] = hwA;                                                \
    Pa[t_j & 1][1][0][pidx] = lwA;                                                \
    Pa[t_j & 1][0][1][pidx] = hwB;                                                \
    Pa[t_j & 1][1][1][pidx] = lwB;                                                \
    lds_barrier();                                                                \
    const bf16x8 ahA = *reinterpret_cast<const bf16x8*>(&Pa[t_j & 1][0][0][aidx]); \
    const bf16x8 alA = *reinterpret_cast<const bf16x8*>(&Pa[t_j & 1][1][0][aidx]); \
    const bf16x8 ahB = *reinterpret_cast<const bf16x8*>(&Pa[t_j & 1][0][1][aidx]); \
    const bf16x8 alB = *reinterpret_cast<const bf16x8*>(&Pa[t_j & 1][1][1][aidx]); \
    accA  = __builtin_amdgcn_mfma_f32_16x16x32_bf16(alA, BHC, accA, 0, 0, 0);     \
    accB  = __builtin_amdgcn_mfma_f32_16x16x32_bf16(alB, BHC, accB, 0, 0, 0);     \
    accA2 = __builtin_amdgcn_mfma_f32_16x16x32_bf16(ahA, BLC, accA2, 0, 0, 0);    \
    accB2 = __builtin_amdgcn_mfma_f32_16x16x32_bf16(ahB, BLC, accB2, 0, 0, 0);    \
    accA  = __builtin_amdgcn_mfma_f32_16x16x32_bf16(ahA, BHC, accA, 0, 0, 0);     \
    accB  = __builtin_amdgcn_mfma_f32_16x16x32_bf16(ahB, BHC, accB, 0, 0, 0);     \
  }

  for (int tj = 0; tj < NT; tj += 2) {
    STEP2(tj,     MA_e, mkA_e, MB_e, mkB_e, nv_e, bh_e, bl_e, bh_o, bl_o)
    STEP2(tj + 1, MA_o, mkA_o, MB_o, mkB_o, nv_o, bh_o, bl_o, bh_e, bl_e)
  }
#undef STEP2

  #pragma unroll
  for (int off = 1; off < 32; off <<= 1) {
    rsumA += __shfl_xor(rsumA, off);
    rsumB += __shfl_xor(rsumB, off);
  }
  if (p2 == 0) { l_lds[r] = rsumA; l_lds[32 + r] = rsumB; }
  __syncthreads();
  if (t < 64) pL[(size_t)jh * 8192 + i0 + t] = l_lds[t];

  float* scratch = nvs;
  if (ks == 1) {
    #pragma unroll
    for (int reg = 0; reg < 4; ++reg)
      scratch[(w & 7) * 256 + reg * 64 + lane] = accA[reg] + accA2[reg];
  }
  __syncthreads();
  if (ks == 0) {
    #pragma unroll
    for (int reg = 0; reg < 4; ++reg) {
      const int row = rb * 16 + (lane >> 4) * 4 + reg;
      pO[(size_t)jh * 8192 * F + (size_t)(i0 + row) * F + col] =
          accA[reg] + accA2[reg] + scratch[(w & 7) * 256 + reg * 64 + lane];
    }
  }
  __syncthreads();
  if (ks == 1) {
    #pragma unroll
    for (int reg = 0; reg < 4; ++reg)
      scratch[(w & 7) * 256 + reg * 64 + lane] = accB[reg] + accB2[reg];
  }
  __syncthreads();
  if (ks == 0) {
    #pragma unroll
    for (int reg = 0; reg < 4; ++reg) {
      const int row = rb * 16 + (lane >> 4) * 4 + reg;
      pO[(size_t)jh * 8192 * F + (size_t)(i0 + 32 + row) * F + col] =
          accB[reg] + accB2[reg] + scratch[(w & 7) * 256 + reg * 64 + lane];
    }
  }
}

// ---------------------------------------------------------------------------
extern "C" void kernel_launch(void* const* d_in, const int* in_sizes, int n_in,
                              void* d_out, int out_size, void* d_ws, size_t ws_size,
                              hipStream_t stream) {
  const float* x   = (const float*)d_in[0];
  const int*   adj = (const int*)  d_in[1];
  const float* Mm  = (const float*)d_in[2];
  const float* W0  = (const float*)d_in[3];
  const float* as0 = (const float*)d_in[4];
  const float* an0 = (const float*)d_in[5];
  const float* W1  = (const float*)d_in[6];
  const float* as1 = (const float*)d_in[7];
  const float* an1 = (const float*)d_in[8];
  float* out = (float*)d_out;

  char* ws = (char*)d_ws;
  const size_t MB = 1048576;
  const size_t KB = 1024;
  float* h0  = (float*)(ws);                              // 8 MB (dead after sn1)
  uint*  Bm  = (uint*) (ws);                              // 8 MB (written after sn1)
  unsigned short* Th0 = (unsigned short*)(ws + 18 * MB);  // 4 MB
  unsigned short* Tl0 = (unsigned short*)(ws + 22 * MB);  // 4 MB
  unsigned short* Th1 = (unsigned short*)(ws + 26 * MB);  // 1 MB
  unsigned short* Tl1 = (unsigned short*)(ws + 27 * MB);  // 1 MB
  float* s0  = (float*)(ws + 28 * MB);
  float* n0  = (float*)(ws + 28 * MB + 32 * KB);
  float* s1  = (float*)(ws + 28 * MB + 64 * KB);
  float* n1  = (float*)(ws + 28 * MB + 96 * KB);
  float* pL1 = (float*)(ws + 28 * MB + 128 * KB);         // 64 KB [2][8192]
  float* pL2 = (float*)(ws + 28 * MB + 192 * KB);         // 64 KB
  float* il1 = (float*)(ws + 28 * MB + 256 * KB);         // 32 KB
  float* pO1 = (float*)(ws + 29 * MB);                    // 16 MB [2][8192][256]
  float* pO2 = (float*)(ws + 29 * MB);                    // 4 MB  [2][8192][64] (pO1 dead)
  unsigned short* Txh = (unsigned short*)(ws + 64 * MB);  // 8 MB (x split hi)
  unsigned short* Txl = (unsigned short*)(ws + 72 * MB);  // 8 MB (x split lo)
  unsigned short* Twh = (unsigned short*)(ws + 80 * MB);  // 256 KB (W0 split hi)
  unsigned short* Twl = (unsigned short*)(ws + 81 * MB);  // 256 KB (W0 split lo)

  // ---- layer 1 ----
  splitx_kernel<<<dim3(512), dim3(256), 0, stream>>>(x, Txh, Txl);
  splitw_kernel<<<dim3(64), dim3(256), 0, stream>>>(W0, Twh, Twl);
  gemm1_mfma_kernel<<<dim3(256), dim3(512), 0, stream>>>(Txh, Txl, Twh, Twl, h0, Th0, Tl0);
  sn_kernel<256><<<dim3(2048), dim3(256), 0, stream>>>(h0, as0, an0, s0, n0);
  mask_kernel<<<dim3(65536), dim3(256), 0, stream>>>(adj, Bm);   // h0 now dead
  attn1_kernel<<<dim3(128, 2), dim3(1024), 0, stream>>>(Mm, Bm, s0, n0, Th0, Tl0, pO1, pL1);
  // ---- layer 2 (combine1+gemm2+sn2+split2 fused) ----
  plsum_kernel<<<dim3(32), dim3(256), 0, stream>>>(pL1, il1);
  gemm2_fused_kernel<<<dim3(128), dim3(256), 0, stream>>>(pO1, il1, W1, as1, an1,
                                                          Th1, Tl1, s1, n1);
  attn2_kernel<<<dim3(128, 2), dim3(1024), 0, stream>>>(Mm, Bm, s1, n1, Th1, Tl1, pO2, pL2);
  combine_kernel<64><<<dim3(512), dim3(256), 0, stream>>>(pO2, pL2, out);
}